// Round 1
// baseline (4797.643 us; speedup 1.0000x reference)
//
#include <hip/hip_runtime.h>

#define NV 100000
#define NE 1600000

#define BM 64
#define BN 64
#define BK 16

// ---------------- degree ----------------
__global__ void degree_count(const int* __restrict__ ef, int* __restrict__ deg, int n) {
    int i = blockIdx.x * blockDim.x + threadIdx.x;
    if (i < n) atomicAdd(&deg[ef[i]], 1);
}

__global__ void make_deg_inv(const int* __restrict__ deg, float* __restrict__ dinv, int n) {
    int i = blockIdx.x * blockDim.x + threadIdx.x;
    if (i < n) dinv[i] = 1.0f / (float)deg[i];
}

// ---------------- GEMM: C[M x dout] = X[M x din] @ W[din x dout] + b ----------------
// 256 threads, 64x64 tile, BK=16, 4x4 microtile per thread.
__global__ __launch_bounds__(256) void gemm_bias(
    const float* __restrict__ X, const float* __restrict__ W,
    const float* __restrict__ bias, float* __restrict__ C,
    int M, int din, int dout)
{
    __shared__ float As[BM][BK + 1];   // +1 pad: conflict-free column reads
    __shared__ float Bs[BK][BN];

    const int tid = threadIdx.x;
    const int bm = blockIdx.x * BM;
    const int bn = blockIdx.y * BN;
    const int tx = tid & 15;    // 16 col groups * 4
    const int ty = tid >> 4;    // 16 row groups * 4

    const int ar = tid >> 2;         // 0..63
    const int ac = (tid & 3) * 4;    // 0,4,8,12
    const int br = tid >> 4;         // 0..15
    const int bc = (tid & 15) * 4;   // 0..60

    float acc[4][4] = {};

    for (int k0 = 0; k0 < din; k0 += BK) {
        // load A tile (X is [M, din], din % 16 == 0 -> float4 aligned)
        {
            const int grow = bm + ar;
            if (grow < M) {
                const float4 v = *reinterpret_cast<const float4*>(&X[(size_t)grow * din + k0 + ac]);
                As[ar][ac + 0] = v.x; As[ar][ac + 1] = v.y;
                As[ar][ac + 2] = v.z; As[ar][ac + 3] = v.w;
            } else {
                As[ar][ac + 0] = 0.f; As[ar][ac + 1] = 0.f;
                As[ar][ac + 2] = 0.f; As[ar][ac + 3] = 0.f;
            }
        }
        // load B tile (W is [din, dout])
        {
            const int gk = k0 + br;
            const int gc = bn + bc;
            float4 v;
            if (gc + 3 < dout) {
                v = *reinterpret_cast<const float4*>(&W[(size_t)gk * dout + gc]);
            } else {
                v.x = (gc + 0 < dout) ? W[(size_t)gk * dout + gc + 0] : 0.f;
                v.y = (gc + 1 < dout) ? W[(size_t)gk * dout + gc + 1] : 0.f;
                v.z = (gc + 2 < dout) ? W[(size_t)gk * dout + gc + 2] : 0.f;
                v.w = (gc + 3 < dout) ? W[(size_t)gk * dout + gc + 3] : 0.f;
            }
            *reinterpret_cast<float4*>(&Bs[br][bc]) = v;
        }
        __syncthreads();

        #pragma unroll
        for (int kk = 0; kk < BK; ++kk) {
            const float a0 = As[ty * 4 + 0][kk];
            const float a1 = As[ty * 4 + 1][kk];
            const float a2 = As[ty * 4 + 2][kk];
            const float a3 = As[ty * 4 + 3][kk];
            const float4 b = *reinterpret_cast<const float4*>(&Bs[kk][tx * 4]);
            acc[0][0] += a0 * b.x; acc[0][1] += a0 * b.y; acc[0][2] += a0 * b.z; acc[0][3] += a0 * b.w;
            acc[1][0] += a1 * b.x; acc[1][1] += a1 * b.y; acc[1][2] += a1 * b.z; acc[1][3] += a1 * b.w;
            acc[2][0] += a2 * b.x; acc[2][1] += a2 * b.y; acc[2][2] += a2 * b.z; acc[2][3] += a2 * b.w;
            acc[3][0] += a3 * b.x; acc[3][1] += a3 * b.y; acc[3][2] += a3 * b.z; acc[3][3] += a3 * b.w;
        }
        __syncthreads();
    }

    #pragma unroll
    for (int i = 0; i < 4; ++i) {
        const int row = bm + ty * 4 + i;
        if (row >= M) continue;
        #pragma unroll
        for (int j = 0; j < 4; ++j) {
            const int col = bn + tx * 4 + j;
            if (col < dout) C[(size_t)row * dout + col] = acc[i][j] + bias[col];
        }
    }
}

// ---------------- edge scatter: acc[e0] += h1[e1]; acc[e1] += h1[e0] ----------------
// one wave (64 lanes) per edge; lanes stride across dout columns.
__global__ __launch_bounds__(256) void scatter_edges(
    const int* __restrict__ edges, const float* __restrict__ h1,
    float* __restrict__ acc, int dout, int nEdges)
{
    const int lane = threadIdx.x & 63;
    int e = blockIdx.x * 4 + (threadIdx.x >> 6);
    if (e >= nEdges) return;
    const int e0 = edges[2 * e];
    const int e1 = edges[2 * e + 1];
    const float* __restrict__ r0 = h1 + (size_t)e0 * dout;
    const float* __restrict__ r1 = h1 + (size_t)e1 * dout;
    float* __restrict__ a0 = acc + (size_t)e0 * dout;
    float* __restrict__ a1 = acc + (size_t)e1 * dout;
    for (int c = lane; c < dout; c += 64) {
        atomicAdd(&a0[c], r1[c]);
        atomicAdd(&a1[c], r0[c]);
    }
}

// ---------------- finalize: out = deg_inv * acc, optional relu ----------------
__global__ void finalize(const float* __restrict__ acc, const float* __restrict__ dinv,
                         float* __restrict__ out, int dout, int nElems, int doRelu)
{
    int i = blockIdx.x * blockDim.x + threadIdx.x;
    if (i >= nElems) return;
    const int v = i / dout;
    float y = acc[i] * dinv[v];
    if (doRelu) y = fmaxf(y, 0.f);
    out[i] = y;
}

extern "C" void kernel_launch(void* const* d_in, const int* in_sizes, int n_in,
                              void* d_out, int out_size, void* d_ws, size_t ws_size,
                              hipStream_t stream) {
    const float* features = (const float*)d_in[0];
    const int*   edges    = (const int*)d_in[1];

    char* ws = (char*)d_ws;
    size_t off = 0;
    auto alloc = [&](size_t bytes) {
        void* p = ws + off;
        off = (off + bytes + 255) & ~(size_t)255;
        return p;
    };
    int*   deg   = (int*)alloc((size_t)NV * sizeof(int));
    float* dinv  = (float*)alloc((size_t)NV * sizeof(float));
    float* acc   = (float*)alloc((size_t)NV * 192 * sizeof(float));
    float* h1    = (float*)alloc((size_t)NV * 192 * sizeof(float));
    float* xbuf  = (float*)alloc((size_t)NV * 192 * sizeof(float));

    // degree + inverse
    hipMemsetAsync(deg, 0, (size_t)NV * sizeof(int), stream);
    degree_count<<<(2 * NE + 255) / 256, 256, 0, stream>>>(edges, deg, 2 * NE);
    make_deg_inv<<<(NV + 255) / 256, 256, 0, stream>>>(deg, dinv, NV);

    const int dims[5] = {256, 192, 128, 64, 3};
    const float* x = features;
    int din = dims[0];

    for (int li = 0; li < 4; ++li) {
        const int dout = dims[li + 1];
        const float* W0 = (const float*)d_in[2 + li * 4 + 0];
        const float* b0 = (const float*)d_in[2 + li * 4 + 1];
        const float* W1 = (const float*)d_in[2 + li * 4 + 2];
        const float* b1 = (const float*)d_in[2 + li * 4 + 3];

        dim3 grid((NV + BM - 1) / BM, (dout + BN - 1) / BN);
        gemm_bias<<<grid, 256, 0, stream>>>(x, W0, b0, acc, NV, din, dout);  // acc = h0
        gemm_bias<<<grid, 256, 0, stream>>>(x, W1, b1, h1,  NV, din, dout);  // h1

        scatter_edges<<<(NE + 3) / 4, 256, 0, stream>>>(edges, h1, acc, dout, NE);

        float* dst = (li < 3) ? xbuf : (float*)d_out;
        const int nElems = NV * dout;
        finalize<<<(nElems + 255) / 256, 256, 0, stream>>>(acc, dinv, dst, dout, nElems, li < 3 ? 1 : 0);

        x = xbuf;
        din = dout;
    }
}

// Round 2
// 1490.523 us; speedup vs baseline: 3.2188x; 3.2188x over previous
//
#include <hip/hip_runtime.h>

#define NV 100000
#define NE 1600000

#define BM 64
#define BN 64
#define BK 16

#define SCAN_B 1024
#define NBLK ((NV + SCAN_B - 1) / SCAN_B)   // 98

// ---------------- degree histogram ----------------
__global__ void degree_count(const int* __restrict__ ef, int* __restrict__ deg, int n) {
    int i = blockIdx.x * blockDim.x + threadIdx.x;
    if (i < n) atomicAdd(&deg[ef[i]], 1);
}

// ---------------- block-level exclusive scan of deg -> rowptr(partial), bsum ----------------
__global__ __launch_bounds__(SCAN_B) void scan_block(const int* __restrict__ deg,
                                                     int* __restrict__ part,
                                                     int* __restrict__ bsum, int n) {
    __shared__ int tmp[SCAN_B];
    const int tid = threadIdx.x;
    const int gid = blockIdx.x * SCAN_B + tid;
    int v = (gid < n) ? deg[gid] : 0;
    tmp[tid] = v;
    __syncthreads();
    for (int off = 1; off < SCAN_B; off <<= 1) {
        int t = (tid >= off) ? tmp[tid - off] : 0;
        __syncthreads();
        tmp[tid] += t;
        __syncthreads();
    }
    if (gid < n) part[gid] = tmp[tid] - v;       // exclusive
    if (tid == SCAN_B - 1) bsum[blockIdx.x] = tmp[tid];
}

// ---------------- scan of block sums (single block, NBLK <= 128) ----------------
__global__ __launch_bounds__(128) void scan_top(int* __restrict__ bsum, int nb) {
    __shared__ int tmp[128];
    const int tid = threadIdx.x;
    int v = (tid < nb) ? bsum[tid] : 0;
    tmp[tid] = v;
    __syncthreads();
    for (int off = 1; off < 128; off <<= 1) {
        int t = (tid >= off) ? tmp[tid - off] : 0;
        __syncthreads();
        tmp[tid] += t;
        __syncthreads();
    }
    if (tid < nb) bsum[tid] = tmp[tid] - v;      // exclusive
}

// ---------------- finalize rowptr, fill cursor copy, deg_inv ----------------
__global__ __launch_bounds__(SCAN_B) void finalize_rowptr(int* __restrict__ rowptr,
                                                          const int* __restrict__ bsum,
                                                          const int* __restrict__ deg,
                                                          int* __restrict__ fill,
                                                          float* __restrict__ dinv, int n) {
    const int gid = blockIdx.x * SCAN_B + threadIdx.x;
    if (gid < n) {
        int r = rowptr[gid] + bsum[blockIdx.x];
        rowptr[gid] = r;
        fill[gid] = r;
        dinv[gid] = 1.0f / (float)deg[gid];
    }
    if (gid == 0) rowptr[n] = 2 * NE;
}

// ---------------- fill adjacency (both directions) ----------------
__global__ void fill_adj(const int* __restrict__ edges, int* __restrict__ fill,
                         int* __restrict__ adj, int nE) {
    int e = blockIdx.x * blockDim.x + threadIdx.x;
    if (e >= nE) return;
    const int a = edges[2 * e];
    const int b = edges[2 * e + 1];
    int pa = atomicAdd(&fill[a], 1); adj[pa] = b;
    int pb = atomicAdd(&fill[b], 1); adj[pb] = a;
}

// ---------------- dual GEMM: C0 = X@W0+b0, C1 = X@W1+b1 ----------------
__global__ __launch_bounds__(256) void gemm_dual_bias(
    const float* __restrict__ X,
    const float* __restrict__ W0, const float* __restrict__ b0,
    const float* __restrict__ W1, const float* __restrict__ b1,
    float* __restrict__ C0, float* __restrict__ C1,
    int M, int din, int dout)
{
    __shared__ float As[BM][BK + 1];
    __shared__ float Bs0[BK][BN];
    __shared__ float Bs1[BK][BN];

    const int tid = threadIdx.x;
    const int bm = blockIdx.x * BM;
    const int bn = blockIdx.y * BN;
    const int tx = tid & 15;
    const int ty = tid >> 4;

    const int ar = tid >> 2;
    const int ac = (tid & 3) * 4;
    const int br = tid >> 4;
    const int bc = (tid & 15) * 4;

    float acc0[4][4] = {};
    float acc1[4][4] = {};

    for (int k0 = 0; k0 < din; k0 += BK) {
        {
            const int grow = bm + ar;
            if (grow < M) {
                const float4 v = *reinterpret_cast<const float4*>(&X[(size_t)grow * din + k0 + ac]);
                As[ar][ac + 0] = v.x; As[ar][ac + 1] = v.y;
                As[ar][ac + 2] = v.z; As[ar][ac + 3] = v.w;
            } else {
                As[ar][ac + 0] = 0.f; As[ar][ac + 1] = 0.f;
                As[ar][ac + 2] = 0.f; As[ar][ac + 3] = 0.f;
            }
        }
        {
            const int gk = k0 + br;
            const int gc = bn + bc;
            float4 v0, v1;
            if (gc + 3 < dout) {
                v0 = *reinterpret_cast<const float4*>(&W0[(size_t)gk * dout + gc]);
                v1 = *reinterpret_cast<const float4*>(&W1[(size_t)gk * dout + gc]);
            } else {
                v0.x = (gc + 0 < dout) ? W0[(size_t)gk * dout + gc + 0] : 0.f;
                v0.y = (gc + 1 < dout) ? W0[(size_t)gk * dout + gc + 1] : 0.f;
                v0.z = (gc + 2 < dout) ? W0[(size_t)gk * dout + gc + 2] : 0.f;
                v0.w = (gc + 3 < dout) ? W0[(size_t)gk * dout + gc + 3] : 0.f;
                v1.x = (gc + 0 < dout) ? W1[(size_t)gk * dout + gc + 0] : 0.f;
                v1.y = (gc + 1 < dout) ? W1[(size_t)gk * dout + gc + 1] : 0.f;
                v1.z = (gc + 2 < dout) ? W1[(size_t)gk * dout + gc + 2] : 0.f;
                v1.w = (gc + 3 < dout) ? W1[(size_t)gk * dout + gc + 3] : 0.f;
            }
            *reinterpret_cast<float4*>(&Bs0[br][bc]) = v0;
            *reinterpret_cast<float4*>(&Bs1[br][bc]) = v1;
        }
        __syncthreads();

        #pragma unroll
        for (int kk = 0; kk < BK; ++kk) {
            const float a0 = As[ty * 4 + 0][kk];
            const float a1 = As[ty * 4 + 1][kk];
            const float a2 = As[ty * 4 + 2][kk];
            const float a3 = As[ty * 4 + 3][kk];
            const float4 p = *reinterpret_cast<const float4*>(&Bs0[kk][tx * 4]);
            const float4 q = *reinterpret_cast<const float4*>(&Bs1[kk][tx * 4]);
            acc0[0][0] += a0 * p.x; acc0[0][1] += a0 * p.y; acc0[0][2] += a0 * p.z; acc0[0][3] += a0 * p.w;
            acc0[1][0] += a1 * p.x; acc0[1][1] += a1 * p.y; acc0[1][2] += a1 * p.z; acc0[1][3] += a1 * p.w;
            acc0[2][0] += a2 * p.x; acc0[2][1] += a2 * p.y; acc0[2][2] += a2 * p.z; acc0[2][3] += a2 * p.w;
            acc0[3][0] += a3 * p.x; acc0[3][1] += a3 * p.y; acc0[3][2] += a3 * p.z; acc0[3][3] += a3 * p.w;
            acc1[0][0] += a0 * q.x; acc1[0][1] += a0 * q.y; acc1[0][2] += a0 * q.z; acc1[0][3] += a0 * q.w;
            acc1[1][0] += a1 * q.x; acc1[1][1] += a1 * q.y; acc1[1][2] += a1 * q.z; acc1[1][3] += a1 * q.w;
            acc1[2][0] += a2 * q.x; acc1[2][1] += a2 * q.y; acc1[2][2] += a2 * q.z; acc1[2][3] += a2 * q.w;
            acc1[3][0] += a3 * q.x; acc1[3][1] += a3 * q.y; acc1[3][2] += a3 * q.z; acc1[3][3] += a3 * q.w;
        }
        __syncthreads();
    }

    #pragma unroll
    for (int i = 0; i < 4; ++i) {
        const int row = bm + ty * 4 + i;
        if (row >= M) continue;
        #pragma unroll
        for (int j = 0; j < 4; ++j) {
            const int col = bn + tx * 4 + j;
            if (col < dout) {
                C0[(size_t)row * dout + col] = acc0[i][j] + b0[col];
                C1[(size_t)row * dout + col] = acc1[i][j] + b1[col];
            }
        }
    }
}

// ---------------- gather + normalize (+relu): out[v] = dinv[v]*(h0[v] + sum_nbr h1[u]) ----------------
// one wave per vertex; lane covers columns lane, lane+64, lane+128.
__global__ __launch_bounds__(256) void gather_norm(
    const float* __restrict__ h0, const float* __restrict__ h1,
    const int* __restrict__ rowptr, const int* __restrict__ adj,
    const float* __restrict__ dinv, float* __restrict__ out,
    int dout, int doRelu)
{
    const int v = blockIdx.x * 4 + (threadIdx.x >> 6);
    if (v >= NV) return;
    const int lane = threadIdx.x & 63;
    const int s = rowptr[v];
    const int e = rowptr[v + 1];
    const int c0 = lane, c1 = lane + 64, c2 = lane + 128;
    const bool h1ok = (c1 < dout), h2ok = (c2 < dout), h0ok = (c0 < dout);

    float a0 = 0.f, a1 = 0.f, a2 = 0.f;
    int j = s;
    for (; j + 4 <= e; j += 4) {
        const float* r0 = h1 + (size_t)adj[j + 0] * dout;
        const float* r1 = h1 + (size_t)adj[j + 1] * dout;
        const float* r2 = h1 + (size_t)adj[j + 2] * dout;
        const float* r3 = h1 + (size_t)adj[j + 3] * dout;
        if (h0ok) a0 += (r0[c0] + r1[c0]) + (r2[c0] + r3[c0]);
        if (h1ok) a1 += (r0[c1] + r1[c1]) + (r2[c1] + r3[c1]);
        if (h2ok) a2 += (r0[c2] + r1[c2]) + (r2[c2] + r3[c2]);
    }
    for (; j < e; ++j) {
        const float* r = h1 + (size_t)adj[j] * dout;
        if (h0ok) a0 += r[c0];
        if (h1ok) a1 += r[c1];
        if (h2ok) a2 += r[c2];
    }

    const float di = dinv[v];
    const size_t base = (size_t)v * dout;
    if (h0ok) {
        float y = (h0[base + c0] + a0) * di;
        out[base + c0] = doRelu ? fmaxf(y, 0.f) : y;
    }
    if (h1ok) {
        float y = (h0[base + c1] + a1) * di;
        out[base + c1] = doRelu ? fmaxf(y, 0.f) : y;
    }
    if (h2ok) {
        float y = (h0[base + c2] + a2) * di;
        out[base + c2] = doRelu ? fmaxf(y, 0.f) : y;
    }
}

extern "C" void kernel_launch(void* const* d_in, const int* in_sizes, int n_in,
                              void* d_out, int out_size, void* d_ws, size_t ws_size,
                              hipStream_t stream) {
    const float* features = (const float*)d_in[0];
    const int*   edges    = (const int*)d_in[1];

    char* ws = (char*)d_ws;
    size_t off = 0;
    auto alloc = [&](size_t bytes) {
        void* p = ws + off;
        off = (off + bytes + 255) & ~(size_t)255;
        return p;
    };
    int*   deg    = (int*)alloc((size_t)NV * sizeof(int));
    float* dinv   = (float*)alloc((size_t)NV * sizeof(float));
    int*   rowptr = (int*)alloc((size_t)(NV + 1) * sizeof(int));
    int*   fill   = (int*)alloc((size_t)NV * sizeof(int));
    int*   bsum   = (int*)alloc(256 * sizeof(int));
    int*   adj    = (int*)alloc((size_t)2 * NE * sizeof(int));
    float* buf0   = (float*)alloc((size_t)NV * 192 * sizeof(float));
    float* buf1   = (float*)alloc((size_t)NV * 192 * sizeof(float));
    float* buf2   = (float*)alloc((size_t)NV * 128 * sizeof(float));

    // ---- CSR build ----
    hipMemsetAsync(deg, 0, (size_t)NV * sizeof(int), stream);
    degree_count<<<(2 * NE + 255) / 256, 256, 0, stream>>>(edges, deg, 2 * NE);
    scan_block<<<NBLK, SCAN_B, 0, stream>>>(deg, rowptr, bsum, NV);
    scan_top<<<1, 128, 0, stream>>>(bsum, NBLK);
    finalize_rowptr<<<NBLK, SCAN_B, 0, stream>>>(rowptr, bsum, deg, fill, dinv, NV);
    fill_adj<<<(NE + 255) / 256, 256, 0, stream>>>(edges, fill, adj, NE);

    // ---- layers ----
    const int dims[5] = {256, 192, 128, 64, 3};
    // buffer rotation: (X, C0, C1) per layer; gather writes in place into C0 (or d_out for last)
    const float* Xp[4];
    float* C0p[4];
    float* C1p[4];
    Xp[0] = features; C0p[0] = buf0; C1p[0] = buf1;
    Xp[1] = buf0;     C0p[1] = buf2; C1p[1] = buf1;
    Xp[2] = buf2;     C0p[2] = buf0; C1p[2] = buf1;
    Xp[3] = buf0;     C0p[3] = buf2; C1p[3] = buf1;

    for (int li = 0; li < 4; ++li) {
        const int din  = dims[li];
        const int dout = dims[li + 1];
        const float* W0 = (const float*)d_in[2 + li * 4 + 0];
        const float* b0 = (const float*)d_in[2 + li * 4 + 1];
        const float* W1 = (const float*)d_in[2 + li * 4 + 2];
        const float* b1 = (const float*)d_in[2 + li * 4 + 3];

        dim3 grid((NV + BM - 1) / BM, (dout + BN - 1) / BN);
        gemm_dual_bias<<<grid, 256, 0, stream>>>(Xp[li], W0, b0, W1, b1, C0p[li], C1p[li],
                                                 NV, din, dout);

        float* dst = (li < 3) ? C0p[li] : (float*)d_out;
        gather_norm<<<(NV + 3) / 4, 256, 0, stream>>>(C0p[li], C1p[li], rowptr, adj, dinv,
                                                      dst, dout, li < 3 ? 1 : 0);
    }
}

// Round 3
// 1408.728 us; speedup vs baseline: 3.4057x; 1.0581x over previous
//
#include <hip/hip_runtime.h>

#define NV 100000
#define NE 1600000

#define BM 64
#define BN 64
#define BK 16

#define SCAN_B 1024
#define NBLK ((NV + SCAN_B - 1) / SCAN_B)   // 98

// ---------------- degree histogram ----------------
__global__ void degree_count(const int* __restrict__ ef, int* __restrict__ deg, int n) {
    int i = blockIdx.x * blockDim.x + threadIdx.x;
    if (i < n) atomicAdd(&deg[ef[i]], 1);
}

// ---------------- block-level exclusive scan of deg -> rowptr(partial), bsum ----------------
__global__ __launch_bounds__(SCAN_B) void scan_block(const int* __restrict__ deg,
                                                     int* __restrict__ part,
                                                     int* __restrict__ bsum, int n) {
    __shared__ int tmp[SCAN_B];
    const int tid = threadIdx.x;
    const int gid = blockIdx.x * SCAN_B + tid;
    int v = (gid < n) ? deg[gid] : 0;
    tmp[tid] = v;
    __syncthreads();
    for (int off = 1; off < SCAN_B; off <<= 1) {
        int t = (tid >= off) ? tmp[tid - off] : 0;
        __syncthreads();
        tmp[tid] += t;
        __syncthreads();
    }
    if (gid < n) part[gid] = tmp[tid] - v;       // exclusive
    if (tid == SCAN_B - 1) bsum[blockIdx.x] = tmp[tid];
}

// ---------------- scan of block sums (single block, NBLK <= 128) ----------------
__global__ __launch_bounds__(128) void scan_top(int* __restrict__ bsum, int nb) {
    __shared__ int tmp[128];
    const int tid = threadIdx.x;
    int v = (tid < nb) ? bsum[tid] : 0;
    tmp[tid] = v;
    __syncthreads();
    for (int off = 1; off < 128; off <<= 1) {
        int t = (tid >= off) ? tmp[tid - off] : 0;
        __syncthreads();
        tmp[tid] += t;
        __syncthreads();
    }
    if (tid < nb) bsum[tid] = tmp[tid] - v;      // exclusive
}

// ---------------- finalize rowptr, fill cursor copy, deg_inv ----------------
__global__ __launch_bounds__(SCAN_B) void finalize_rowptr(int* __restrict__ rowptr,
                                                          const int* __restrict__ bsum,
                                                          const int* __restrict__ deg,
                                                          int* __restrict__ fill,
                                                          float* __restrict__ dinv, int n) {
    const int gid = blockIdx.x * SCAN_B + threadIdx.x;
    if (gid < n) {
        int r = rowptr[gid] + bsum[blockIdx.x];
        rowptr[gid] = r;
        fill[gid] = r;
        dinv[gid] = 1.0f / (float)deg[gid];
    }
    if (gid == 0) rowptr[n] = 2 * NE;
}

// ---------------- fill adjacency (both directions) ----------------
__global__ void fill_adj(const int* __restrict__ edges, int* __restrict__ fill,
                         int* __restrict__ adj, int nE) {
    int e = blockIdx.x * blockDim.x + threadIdx.x;
    if (e >= nE) return;
    const int a = edges[2 * e];
    const int b = edges[2 * e + 1];
    int pa = atomicAdd(&fill[a], 1); adj[pa] = b;
    int pb = atomicAdd(&fill[b], 1); adj[pb] = a;
}

// ---------------- dual GEMM: C0 = X@W0+b0, C1 = X@W1+b1 ----------------
__global__ __launch_bounds__(256) void gemm_dual_bias(
    const float* __restrict__ X,
    const float* __restrict__ W0, const float* __restrict__ b0,
    const float* __restrict__ W1, const float* __restrict__ b1,
    float* __restrict__ C0, float* __restrict__ C1,
    int M, int din, int dout)
{
    __shared__ float As[BM][BK + 1];
    __shared__ float Bs0[BK][BN];
    __shared__ float Bs1[BK][BN];

    const int tid = threadIdx.x;
    const int bm = blockIdx.x * BM;
    const int bn = blockIdx.y * BN;
    const int tx = tid & 15;
    const int ty = tid >> 4;

    const int ar = tid >> 2;
    const int ac = (tid & 3) * 4;
    const int br = tid >> 4;
    const int bc = (tid & 15) * 4;

    float acc0[4][4] = {};
    float acc1[4][4] = {};

    for (int k0 = 0; k0 < din; k0 += BK) {
        {
            const int grow = bm + ar;
            if (grow < M) {
                const float4 v = *reinterpret_cast<const float4*>(&X[(size_t)grow * din + k0 + ac]);
                As[ar][ac + 0] = v.x; As[ar][ac + 1] = v.y;
                As[ar][ac + 2] = v.z; As[ar][ac + 3] = v.w;
            } else {
                As[ar][ac + 0] = 0.f; As[ar][ac + 1] = 0.f;
                As[ar][ac + 2] = 0.f; As[ar][ac + 3] = 0.f;
            }
        }
        {
            const int gk = k0 + br;
            const int gc = bn + bc;
            float4 v0, v1;
            if (gc + 3 < dout) {
                v0 = *reinterpret_cast<const float4*>(&W0[(size_t)gk * dout + gc]);
                v1 = *reinterpret_cast<const float4*>(&W1[(size_t)gk * dout + gc]);
            } else {
                v0.x = (gc + 0 < dout) ? W0[(size_t)gk * dout + gc + 0] : 0.f;
                v0.y = (gc + 1 < dout) ? W0[(size_t)gk * dout + gc + 1] : 0.f;
                v0.z = (gc + 2 < dout) ? W0[(size_t)gk * dout + gc + 2] : 0.f;
                v0.w = (gc + 3 < dout) ? W0[(size_t)gk * dout + gc + 3] : 0.f;
                v1.x = (gc + 0 < dout) ? W1[(size_t)gk * dout + gc + 0] : 0.f;
                v1.y = (gc + 1 < dout) ? W1[(size_t)gk * dout + gc + 1] : 0.f;
                v1.z = (gc + 2 < dout) ? W1[(size_t)gk * dout + gc + 2] : 0.f;
                v1.w = (gc + 3 < dout) ? W1[(size_t)gk * dout + gc + 3] : 0.f;
            }
            *reinterpret_cast<float4*>(&Bs0[br][bc]) = v0;
            *reinterpret_cast<float4*>(&Bs1[br][bc]) = v1;
        }
        __syncthreads();

        #pragma unroll
        for (int kk = 0; kk < BK; ++kk) {
            const float a0 = As[ty * 4 + 0][kk];
            const float a1 = As[ty * 4 + 1][kk];
            const float a2 = As[ty * 4 + 2][kk];
            const float a3 = As[ty * 4 + 3][kk];
            const float4 p = *reinterpret_cast<const float4*>(&Bs0[kk][tx * 4]);
            const float4 q = *reinterpret_cast<const float4*>(&Bs1[kk][tx * 4]);
            acc0[0][0] += a0 * p.x; acc0[0][1] += a0 * p.y; acc0[0][2] += a0 * p.z; acc0[0][3] += a0 * p.w;
            acc0[1][0] += a1 * p.x; acc0[1][1] += a1 * p.y; acc0[1][2] += a1 * p.z; acc0[1][3] += a1 * p.w;
            acc0[2][0] += a2 * p.x; acc0[2][1] += a2 * p.y; acc0[2][2] += a2 * p.z; acc0[2][3] += a2 * p.w;
            acc0[3][0] += a3 * p.x; acc0[3][1] += a3 * p.y; acc0[3][2] += a3 * p.z; acc0[3][3] += a3 * p.w;
            acc1[0][0] += a0 * q.x; acc1[0][1] += a0 * q.y; acc1[0][2] += a0 * q.z; acc1[0][3] += a0 * q.w;
            acc1[1][0] += a1 * q.x; acc1[1][1] += a1 * q.y; acc1[1][2] += a1 * q.z; acc1[1][3] += a1 * q.w;
            acc1[2][0] += a2 * q.x; acc1[2][1] += a2 * q.y; acc1[2][2] += a2 * q.z; acc1[2][3] += a2 * q.w;
            acc1[3][0] += a3 * q.x; acc1[3][1] += a3 * q.y; acc1[3][2] += a3 * q.z; acc1[3][3] += a3 * q.w;
        }
        __syncthreads();
    }

    #pragma unroll
    for (int i = 0; i < 4; ++i) {
        const int row = bm + ty * 4 + i;
        if (row >= M) continue;
        #pragma unroll
        for (int j = 0; j < 4; ++j) {
            const int col = bn + tx * 4 + j;
            if (col < dout) {
                C0[(size_t)row * dout + col] = acc0[i][j] + b0[col];
                C1[(size_t)row * dout + col] = acc1[i][j] + b1[col];
            }
        }
    }
}

// ---------------- gathers (width-specialized) ----------------
// dout=192: one wave per vertex, all 64 lanes, float3 per lane (64*12B = 768B/row)
__global__ __launch_bounds__(256) void gather_d192(
    const float* __restrict__ h0, const float* __restrict__ h1,
    const int* __restrict__ rowptr, const int* __restrict__ adj,
    const float* __restrict__ dinv, float* __restrict__ out)
{
    const int v = blockIdx.x * 4 + (threadIdx.x >> 6);
    if (v >= NV) return;
    const int lane = threadIdx.x & 63;
    const int s = rowptr[v], e = rowptr[v + 1];
    const int col = lane * 3;
    float a0 = 0.f, a1 = 0.f, a2 = 0.f;

    int j = s;
    const int jend = s + ((e - s) & ~3);
    for (; j < jend; j += 4) {
        const int u0 = adj[j + 0], u1 = adj[j + 1], u2 = adj[j + 2], u3 = adj[j + 3];
        const float3 r0 = *reinterpret_cast<const float3*>(h1 + (size_t)u0 * 192 + col);
        const float3 r1 = *reinterpret_cast<const float3*>(h1 + (size_t)u1 * 192 + col);
        const float3 r2 = *reinterpret_cast<const float3*>(h1 + (size_t)u2 * 192 + col);
        const float3 r3 = *reinterpret_cast<const float3*>(h1 + (size_t)u3 * 192 + col);
        a0 += (r0.x + r1.x) + (r2.x + r3.x);
        a1 += (r0.y + r1.y) + (r2.y + r3.y);
        a2 += (r0.z + r1.z) + (r2.z + r3.z);
    }
    for (; j < e; ++j) {
        const float3 r = *reinterpret_cast<const float3*>(h1 + (size_t)adj[j] * 192 + col);
        a0 += r.x; a1 += r.y; a2 += r.z;
    }

    const float di = dinv[v];
    const size_t base = (size_t)v * 192 + col;
    float3 o;
    o.x = fmaxf((h0[base + 0] + a0) * di, 0.f);
    o.y = fmaxf((h0[base + 1] + a1) * di, 0.f);
    o.z = fmaxf((h0[base + 2] + a2) * di, 0.f);
    *reinterpret_cast<float3*>(out + base) = o;
}

// dout=128: 2 neighbors per wave (32 lanes x float4 each), shfl_xor(32) reduce
__global__ __launch_bounds__(256) void gather_d128(
    const float* __restrict__ h0, const float* __restrict__ h1,
    const int* __restrict__ rowptr, const int* __restrict__ adj,
    const float* __restrict__ dinv, float* __restrict__ out)
{
    const int v = blockIdx.x * 4 + (threadIdx.x >> 6);
    if (v >= NV) return;
    const int lane = threadIdx.x & 63;
    const int sub = lane >> 5;          // 0/1: which neighbor of the pair
    const int col = (lane & 31) * 4;
    const int s = rowptr[v], e = rowptr[v + 1];
    float4 acc = {0.f, 0.f, 0.f, 0.f};

    int j = s;
    const int jend = s + ((e - s) & ~3);
    for (; j < jend; j += 4) {
        const int u0 = adj[j + sub];
        const int u1 = adj[j + 2 + sub];
        const float4 r0 = *reinterpret_cast<const float4*>(h1 + (size_t)u0 * 128 + col);
        const float4 r1 = *reinterpret_cast<const float4*>(h1 + (size_t)u1 * 128 + col);
        acc.x += r0.x + r1.x; acc.y += r0.y + r1.y;
        acc.z += r0.z + r1.z; acc.w += r0.w + r1.w;
    }
    for (; j < e; j += 2) {
        const int jj = j + sub;
        if (jj < e) {
            const float4 r = *reinterpret_cast<const float4*>(h1 + (size_t)adj[jj] * 128 + col);
            acc.x += r.x; acc.y += r.y; acc.z += r.z; acc.w += r.w;
        }
    }

    acc.x += __shfl_xor(acc.x, 32);
    acc.y += __shfl_xor(acc.y, 32);
    acc.z += __shfl_xor(acc.z, 32);
    acc.w += __shfl_xor(acc.w, 32);

    if (sub == 0) {
        const float di = dinv[v];
        const size_t base = (size_t)v * 128 + col;
        float4 o;
        o.x = fmaxf((h0[base + 0] + acc.x) * di, 0.f);
        o.y = fmaxf((h0[base + 1] + acc.y) * di, 0.f);
        o.z = fmaxf((h0[base + 2] + acc.z) * di, 0.f);
        o.w = fmaxf((h0[base + 3] + acc.w) * di, 0.f);
        *reinterpret_cast<float4*>(out + base) = o;
    }
}

// dout=64: 4 neighbors per wave (16 lanes x float4 each), shfl_xor(16,32) reduce
__global__ __launch_bounds__(256) void gather_d64(
    const float* __restrict__ h0, const float* __restrict__ h1,
    const int* __restrict__ rowptr, const int* __restrict__ adj,
    const float* __restrict__ dinv, float* __restrict__ out)
{
    const int v = blockIdx.x * 4 + (threadIdx.x >> 6);
    if (v >= NV) return;
    const int lane = threadIdx.x & 63;
    const int sub = lane >> 4;          // 0..3
    const int col = (lane & 15) * 4;
    const int s = rowptr[v], e = rowptr[v + 1];
    float4 acc = {0.f, 0.f, 0.f, 0.f};

    int j = s;
    const int jend = s + ((e - s) & ~7);
    for (; j < jend; j += 8) {
        const int u0 = adj[j + sub];
        const int u1 = adj[j + 4 + sub];
        const float4 r0 = *reinterpret_cast<const float4*>(h1 + (size_t)u0 * 64 + col);
        const float4 r1 = *reinterpret_cast<const float4*>(h1 + (size_t)u1 * 64 + col);
        acc.x += r0.x + r1.x; acc.y += r0.y + r1.y;
        acc.z += r0.z + r1.z; acc.w += r0.w + r1.w;
    }
    for (; j < e; j += 4) {
        const int jj = j + sub;
        if (jj < e) {
            const float4 r = *reinterpret_cast<const float4*>(h1 + (size_t)adj[jj] * 64 + col);
            acc.x += r.x; acc.y += r.y; acc.z += r.z; acc.w += r.w;
        }
    }

    acc.x += __shfl_xor(acc.x, 16); acc.y += __shfl_xor(acc.y, 16);
    acc.z += __shfl_xor(acc.z, 16); acc.w += __shfl_xor(acc.w, 16);
    acc.x += __shfl_xor(acc.x, 32); acc.y += __shfl_xor(acc.y, 32);
    acc.z += __shfl_xor(acc.z, 32); acc.w += __shfl_xor(acc.w, 32);

    if (sub == 0) {
        const float di = dinv[v];
        const size_t base = (size_t)v * 64 + col;
        float4 o;
        o.x = fmaxf((h0[base + 0] + acc.x) * di, 0.f);
        o.y = fmaxf((h0[base + 1] + acc.y) * di, 0.f);
        o.z = fmaxf((h0[base + 2] + acc.z) * di, 0.f);
        o.w = fmaxf((h0[base + 3] + acc.w) * di, 0.f);
        *reinterpret_cast<float4*>(out + base) = o;
    }
}

// dout=3 (last layer, no relu): lane-per-neighbor, butterfly reduce
__global__ __launch_bounds__(256) void gather_d3(
    const float* __restrict__ h0, const float* __restrict__ h1,
    const int* __restrict__ rowptr, const int* __restrict__ adj,
    const float* __restrict__ dinv, float* __restrict__ out)
{
    const int v = blockIdx.x * 4 + (threadIdx.x >> 6);
    if (v >= NV) return;
    const int lane = threadIdx.x & 63;
    const int s = rowptr[v], e = rowptr[v + 1];
    float a0 = 0.f, a1 = 0.f, a2 = 0.f;
    for (int j = s + lane; j < e; j += 64) {
        const float3 r = *reinterpret_cast<const float3*>(h1 + (size_t)adj[j] * 3);
        a0 += r.x; a1 += r.y; a2 += r.z;
    }
    #pragma unroll
    for (int off = 1; off < 64; off <<= 1) {
        a0 += __shfl_xor(a0, off);
        a1 += __shfl_xor(a1, off);
        a2 += __shfl_xor(a2, off);
    }
    if (lane == 0) {
        const float di = dinv[v];
        const size_t base = (size_t)v * 3;
        out[base + 0] = (h0[base + 0] + a0) * di;
        out[base + 1] = (h0[base + 1] + a1) * di;
        out[base + 2] = (h0[base + 2] + a2) * di;
    }
}

extern "C" void kernel_launch(void* const* d_in, const int* in_sizes, int n_in,
                              void* d_out, int out_size, void* d_ws, size_t ws_size,
                              hipStream_t stream) {
    const float* features = (const float*)d_in[0];
    const int*   edges    = (const int*)d_in[1];

    char* ws = (char*)d_ws;
    size_t off = 0;
    auto alloc = [&](size_t bytes) {
        void* p = ws + off;
        off = (off + bytes + 255) & ~(size_t)255;
        return p;
    };
    int*   deg    = (int*)alloc((size_t)NV * sizeof(int));
    float* dinv   = (float*)alloc((size_t)NV * sizeof(float));
    int*   rowptr = (int*)alloc((size_t)(NV + 1) * sizeof(int));
    int*   fill   = (int*)alloc((size_t)NV * sizeof(int));
    int*   bsum   = (int*)alloc(256 * sizeof(int));
    int*   adj    = (int*)alloc((size_t)2 * NE * sizeof(int));
    float* buf0   = (float*)alloc((size_t)NV * 192 * sizeof(float));
    float* buf1   = (float*)alloc((size_t)NV * 192 * sizeof(float));
    float* buf2   = (float*)alloc((size_t)NV * 128 * sizeof(float));

    // ---- CSR build ----
    hipMemsetAsync(deg, 0, (size_t)NV * sizeof(int), stream);
    degree_count<<<(2 * NE + 255) / 256, 256, 0, stream>>>(edges, deg, 2 * NE);
    scan_block<<<NBLK, SCAN_B, 0, stream>>>(deg, rowptr, bsum, NV);
    scan_top<<<1, 128, 0, stream>>>(bsum, NBLK);
    finalize_rowptr<<<NBLK, SCAN_B, 0, stream>>>(rowptr, bsum, deg, fill, dinv, NV);
    fill_adj<<<(NE + 255) / 256, 256, 0, stream>>>(edges, fill, adj, NE);

    // ---- layers ----
    const int dims[5] = {256, 192, 128, 64, 3};
    const float* Xp[4];
    float* C0p[4];
    float* C1p[4];
    Xp[0] = features; C0p[0] = buf0; C1p[0] = buf1;
    Xp[1] = buf0;     C0p[1] = buf2; C1p[1] = buf1;
    Xp[2] = buf2;     C0p[2] = buf0; C1p[2] = buf1;
    Xp[3] = buf0;     C0p[3] = buf2; C1p[3] = buf1;

    const int gatherGrid = (NV + 3) / 4;

    for (int li = 0; li < 4; ++li) {
        const int din  = dims[li];
        const int dout = dims[li + 1];
        const float* W0 = (const float*)d_in[2 + li * 4 + 0];
        const float* b0 = (const float*)d_in[2 + li * 4 + 1];
        const float* W1 = (const float*)d_in[2 + li * 4 + 2];
        const float* b1 = (const float*)d_in[2 + li * 4 + 3];

        dim3 grid((NV + BM - 1) / BM, (dout + BN - 1) / BN);
        gemm_dual_bias<<<grid, 256, 0, stream>>>(Xp[li], W0, b0, W1, b1, C0p[li], C1p[li],
                                                 NV, din, dout);

        float* dst = (li < 3) ? C0p[li] : (float*)d_out;
        if (li == 0)      gather_d192<<<gatherGrid, 256, 0, stream>>>(C0p[li], C1p[li], rowptr, adj, dinv, dst);
        else if (li == 1) gather_d128<<<gatherGrid, 256, 0, stream>>>(C0p[li], C1p[li], rowptr, adj, dinv, dst);
        else if (li == 2) gather_d64 <<<gatherGrid, 256, 0, stream>>>(C0p[li], C1p[li], rowptr, adj, dinv, dst);
        else              gather_d3  <<<gatherGrid, 256, 0, stream>>>(C0p[li], C1p[li], rowptr, adj, dinv, dst);
    }
}

// Round 4
// 1081.807 us; speedup vs baseline: 4.4348x; 1.3022x over previous
//
#include <hip/hip_runtime.h>
#include <hip/hip_fp16.h>

#define NV 100000
#define NE 1600000

#define BM 64
#define BN 64
#define BK 16

#define SCAN_B 1024
#define NBLK ((NV + SCAN_B - 1) / SCAN_B)   // 98

// ---------------- degree histogram ----------------
__global__ void degree_count(const int* __restrict__ ef, int* __restrict__ deg, int n) {
    int i = blockIdx.x * blockDim.x + threadIdx.x;
    if (i < n) atomicAdd(&deg[ef[i]], 1);
}

// ---------------- block-level exclusive scan of deg -> rowptr(partial), bsum ----------------
__global__ __launch_bounds__(SCAN_B) void scan_block(const int* __restrict__ deg,
                                                     int* __restrict__ part,
                                                     int* __restrict__ bsum, int n) {
    __shared__ int tmp[SCAN_B];
    const int tid = threadIdx.x;
    const int gid = blockIdx.x * SCAN_B + tid;
    int v = (gid < n) ? deg[gid] : 0;
    tmp[tid] = v;
    __syncthreads();
    for (int off = 1; off < SCAN_B; off <<= 1) {
        int t = (tid >= off) ? tmp[tid - off] : 0;
        __syncthreads();
        tmp[tid] += t;
        __syncthreads();
    }
    if (gid < n) part[gid] = tmp[tid] - v;       // exclusive
    if (tid == SCAN_B - 1) bsum[blockIdx.x] = tmp[tid];
}

// ---------------- scan of block sums (single block) ----------------
__global__ __launch_bounds__(128) void scan_top(int* __restrict__ bsum, int nb) {
    __shared__ int tmp[128];
    const int tid = threadIdx.x;
    int v = (tid < nb) ? bsum[tid] : 0;
    tmp[tid] = v;
    __syncthreads();
    for (int off = 1; off < 128; off <<= 1) {
        int t = (tid >= off) ? tmp[tid - off] : 0;
        __syncthreads();
        tmp[tid] += t;
        __syncthreads();
    }
    if (tid < nb) bsum[tid] = tmp[tid] - v;      // exclusive
}

// ---------------- finalize rowptr, fill cursor copy, deg_inv ----------------
__global__ __launch_bounds__(SCAN_B) void finalize_rowptr(int* __restrict__ rowptr,
                                                          const int* __restrict__ bsum,
                                                          const int* __restrict__ deg,
                                                          int* __restrict__ fill,
                                                          float* __restrict__ dinv, int n) {
    const int gid = blockIdx.x * SCAN_B + threadIdx.x;
    if (gid < n) {
        int r = rowptr[gid] + bsum[blockIdx.x];
        rowptr[gid] = r;
        fill[gid] = r;
        dinv[gid] = 1.0f / (float)deg[gid];
    }
    if (gid == 0) rowptr[n] = 2 * NE;
}

// ---------------- fill adjacency (both directions) ----------------
__global__ void fill_adj(const int* __restrict__ edges, int* __restrict__ fill,
                         int* __restrict__ adj, int nE) {
    int e = blockIdx.x * blockDim.x + threadIdx.x;
    if (e >= nE) return;
    const int a = edges[2 * e];
    const int b = edges[2 * e + 1];
    int pa = atomicAdd(&fill[a], 1); adj[pa] = b;
    int pb = atomicAdd(&fill[b], 1); adj[pb] = a;
}

// ---------------- dual GEMM: C0 = X@W0+b0 (fp32), C1 = X@W1+b1 (fp16 if HALF1) ----------------
template <bool HALF1>
__global__ __launch_bounds__(256) void gemm_dual_bias(
    const float* __restrict__ X,
    const float* __restrict__ W0, const float* __restrict__ b0,
    const float* __restrict__ W1, const float* __restrict__ b1,
    float* __restrict__ C0, void* __restrict__ C1v,
    int M, int din, int dout)
{
    __shared__ float As[BM][BK + 1];
    __shared__ float Bs0[BK][BN];
    __shared__ float Bs1[BK][BN];

    const int tid = threadIdx.x;
    const int bm = blockIdx.x * BM;
    const int bn = blockIdx.y * BN;
    const int tx = tid & 15;
    const int ty = tid >> 4;

    const int ar = tid >> 2;
    const int ac = (tid & 3) * 4;
    const int br = tid >> 4;
    const int bc = (tid & 15) * 4;

    float acc0[4][4] = {};
    float acc1[4][4] = {};

    for (int k0 = 0; k0 < din; k0 += BK) {
        {
            const int grow = bm + ar;
            if (grow < M) {
                const float4 v = *reinterpret_cast<const float4*>(&X[(size_t)grow * din + k0 + ac]);
                As[ar][ac + 0] = v.x; As[ar][ac + 1] = v.y;
                As[ar][ac + 2] = v.z; As[ar][ac + 3] = v.w;
            } else {
                As[ar][ac + 0] = 0.f; As[ar][ac + 1] = 0.f;
                As[ar][ac + 2] = 0.f; As[ar][ac + 3] = 0.f;
            }
        }
        {
            const int gk = k0 + br;
            const int gc = bn + bc;
            float4 v0, v1;
            if (gc + 3 < dout) {
                v0 = *reinterpret_cast<const float4*>(&W0[(size_t)gk * dout + gc]);
                v1 = *reinterpret_cast<const float4*>(&W1[(size_t)gk * dout + gc]);
            } else {
                v0.x = (gc + 0 < dout) ? W0[(size_t)gk * dout + gc + 0] : 0.f;
                v0.y = (gc + 1 < dout) ? W0[(size_t)gk * dout + gc + 1] : 0.f;
                v0.z = (gc + 2 < dout) ? W0[(size_t)gk * dout + gc + 2] : 0.f;
                v0.w = (gc + 3 < dout) ? W0[(size_t)gk * dout + gc + 3] : 0.f;
                v1.x = (gc + 0 < dout) ? W1[(size_t)gk * dout + gc + 0] : 0.f;
                v1.y = (gc + 1 < dout) ? W1[(size_t)gk * dout + gc + 1] : 0.f;
                v1.z = (gc + 2 < dout) ? W1[(size_t)gk * dout + gc + 2] : 0.f;
                v1.w = (gc + 3 < dout) ? W1[(size_t)gk * dout + gc + 3] : 0.f;
            }
            *reinterpret_cast<float4*>(&Bs0[br][bc]) = v0;
            *reinterpret_cast<float4*>(&Bs1[br][bc]) = v1;
        }
        __syncthreads();

        #pragma unroll
        for (int kk = 0; kk < BK; ++kk) {
            const float a0 = As[ty * 4 + 0][kk];
            const float a1 = As[ty * 4 + 1][kk];
            const float a2 = As[ty * 4 + 2][kk];
            const float a3 = As[ty * 4 + 3][kk];
            const float4 p = *reinterpret_cast<const float4*>(&Bs0[kk][tx * 4]);
            const float4 q = *reinterpret_cast<const float4*>(&Bs1[kk][tx * 4]);
            acc0[0][0] += a0 * p.x; acc0[0][1] += a0 * p.y; acc0[0][2] += a0 * p.z; acc0[0][3] += a0 * p.w;
            acc0[1][0] += a1 * p.x; acc0[1][1] += a1 * p.y; acc0[1][2] += a1 * p.z; acc0[1][3] += a1 * p.w;
            acc0[2][0] += a2 * p.x; acc0[2][1] += a2 * p.y; acc0[2][2] += a2 * p.z; acc0[2][3] += a2 * p.w;
            acc0[3][0] += a3 * p.x; acc0[3][1] += a3 * p.y; acc0[3][2] += a3 * p.z; acc0[3][3] += a3 * p.w;
            acc1[0][0] += a0 * q.x; acc1[0][1] += a0 * q.y; acc1[0][2] += a0 * q.z; acc1[0][3] += a0 * q.w;
            acc1[1][0] += a1 * q.x; acc1[1][1] += a1 * q.y; acc1[1][2] += a1 * q.z; acc1[1][3] += a1 * q.w;
            acc1[2][0] += a2 * q.x; acc1[2][1] += a2 * q.y; acc1[2][2] += a2 * q.z; acc1[2][3] += a2 * q.w;
            acc1[3][0] += a3 * q.x; acc1[3][1] += a3 * q.y; acc1[3][2] += a3 * q.z; acc1[3][3] += a3 * q.w;
        }
        __syncthreads();
    }

    #pragma unroll
    for (int i = 0; i < 4; ++i) {
        const int row = bm + ty * 4 + i;
        if (row >= M) continue;
        #pragma unroll
        for (int j = 0; j < 4; ++j) {
            const int col = bn + tx * 4 + j;
            if (col < dout) {
                C0[(size_t)row * dout + col] = acc0[i][j] + b0[col];
                if (HALF1) {
                    ((__half*)C1v)[(size_t)row * dout + col] = __float2half(acc1[i][j] + b1[col]);
                } else {
                    ((float*)C1v)[(size_t)row * dout + col] = acc1[i][j] + b1[col];
                }
            }
        }
    }
}

// ---------------- gathers over fp16 h1 ----------------
// dout=192: 2 neighbors/wave; 32 lanes x 3 half2 (12B) each; shfl_xor(32) combine.
__global__ __launch_bounds__(256) void gather_d192_h(
    const float* __restrict__ h0, const __half2* __restrict__ h1,
    const int* __restrict__ rowptr, const int* __restrict__ adj,
    const float* __restrict__ dinv, float* __restrict__ out)
{
    const int v = blockIdx.x * 4 + (threadIdx.x >> 6);
    if (v >= NV) return;
    const int lane = threadIdx.x & 63;
    const int sub = lane >> 5;             // neighbor parity
    const int cu = (lane & 31) * 3;        // half2 column
    const int s = rowptr[v], e = rowptr[v + 1];

    float2 a0 = {0.f, 0.f}, a1 = {0.f, 0.f}, a2 = {0.f, 0.f};

    int j = s;
    const int jend = s + ((e - s) & ~3);
    for (; j < jend; j += 4) {
        const __half2* r0 = h1 + (size_t)adj[j + sub] * 96 + cu;
        const __half2* r1 = h1 + (size_t)adj[j + 2 + sub] * 96 + cu;
        const float2 p0 = __half22float2(r0[0]);
        const float2 p1 = __half22float2(r0[1]);
        const float2 p2 = __half22float2(r0[2]);
        const float2 q0 = __half22float2(r1[0]);
        const float2 q1 = __half22float2(r1[1]);
        const float2 q2 = __half22float2(r1[2]);
        a0.x += p0.x + q0.x; a0.y += p0.y + q0.y;
        a1.x += p1.x + q1.x; a1.y += p1.y + q1.y;
        a2.x += p2.x + q2.x; a2.y += p2.y + q2.y;
    }
    for (; j < e; j += 2) {
        const int jj = j + sub;
        if (jj < e) {
            const __half2* r = h1 + (size_t)adj[jj] * 96 + cu;
            const float2 p0 = __half22float2(r[0]);
            const float2 p1 = __half22float2(r[1]);
            const float2 p2 = __half22float2(r[2]);
            a0.x += p0.x; a0.y += p0.y;
            a1.x += p1.x; a1.y += p1.y;
            a2.x += p2.x; a2.y += p2.y;
        }
    }

    a0.x += __shfl_xor(a0.x, 32); a0.y += __shfl_xor(a0.y, 32);
    a1.x += __shfl_xor(a1.x, 32); a1.y += __shfl_xor(a1.y, 32);
    a2.x += __shfl_xor(a2.x, 32); a2.y += __shfl_xor(a2.y, 32);

    if (sub == 0) {
        const float di = dinv[v];
        const size_t base = (size_t)v * 192 + (size_t)cu * 2;
        float2 o0, o1, o2;
        o0.x = fmaxf((h0[base + 0] + a0.x) * di, 0.f);
        o0.y = fmaxf((h0[base + 1] + a0.y) * di, 0.f);
        o1.x = fmaxf((h0[base + 2] + a1.x) * di, 0.f);
        o1.y = fmaxf((h0[base + 3] + a1.y) * di, 0.f);
        o2.x = fmaxf((h0[base + 4] + a2.x) * di, 0.f);
        o2.y = fmaxf((h0[base + 5] + a2.y) * di, 0.f);
        *reinterpret_cast<float2*>(out + base + 0) = o0;
        *reinterpret_cast<float2*>(out + base + 2) = o1;
        *reinterpret_cast<float2*>(out + base + 4) = o2;
    }
}

// dout=128: 4 neighbors/wave; 16 lanes x 4 half2 (16B) each; shfl_xor(16,32).
__global__ __launch_bounds__(256) void gather_d128_h(
    const float* __restrict__ h0, const __half2* __restrict__ h1,
    const int* __restrict__ rowptr, const int* __restrict__ adj,
    const float* __restrict__ dinv, float* __restrict__ out)
{
    const int v = blockIdx.x * 4 + (threadIdx.x >> 6);
    if (v >= NV) return;
    const int lane = threadIdx.x & 63;
    const int sub = lane >> 4;             // 0..3
    const int cu = (lane & 15) * 4;        // half2 column
    const int s = rowptr[v], e = rowptr[v + 1];

    float acc[8] = {};

    int j = s;
    const int jend = s + ((e - s) & ~7);
    for (; j < jend; j += 8) {
        const int4 w0 = *reinterpret_cast<const int4*>(h1 + (size_t)adj[j + sub] * 64 + cu);
        const int4 w1 = *reinterpret_cast<const int4*>(h1 + (size_t)adj[j + 4 + sub] * 64 + cu);
        #pragma unroll
        for (int t = 0; t < 4; ++t) {
            const float2 p = __half22float2(*(const __half2*)(&(&w0.x)[t]));
            const float2 q = __half22float2(*(const __half2*)(&(&w1.x)[t]));
            acc[2 * t + 0] += p.x + q.x;
            acc[2 * t + 1] += p.y + q.y;
        }
    }
    for (; j < e; j += 4) {
        const int jj = j + sub;
        if (jj < e) {
            const int4 w0 = *reinterpret_cast<const int4*>(h1 + (size_t)adj[jj] * 64 + cu);
            #pragma unroll
            for (int t = 0; t < 4; ++t) {
                const float2 p = __half22float2(*(const __half2*)(&(&w0.x)[t]));
                acc[2 * t + 0] += p.x;
                acc[2 * t + 1] += p.y;
            }
        }
    }

    #pragma unroll
    for (int t = 0; t < 8; ++t) {
        acc[t] += __shfl_xor(acc[t], 16);
        acc[t] += __shfl_xor(acc[t], 32);
    }

    if (sub == 0) {
        const float di = dinv[v];
        const size_t base = (size_t)v * 128 + (size_t)cu * 2;
        float4 o0, o1;
        o0.x = fmaxf((h0[base + 0] + acc[0]) * di, 0.f);
        o0.y = fmaxf((h0[base + 1] + acc[1]) * di, 0.f);
        o0.z = fmaxf((h0[base + 2] + acc[2]) * di, 0.f);
        o0.w = fmaxf((h0[base + 3] + acc[3]) * di, 0.f);
        o1.x = fmaxf((h0[base + 4] + acc[4]) * di, 0.f);
        o1.y = fmaxf((h0[base + 5] + acc[5]) * di, 0.f);
        o1.z = fmaxf((h0[base + 6] + acc[6]) * di, 0.f);
        o1.w = fmaxf((h0[base + 7] + acc[7]) * di, 0.f);
        *reinterpret_cast<float4*>(out + base + 0) = o0;
        *reinterpret_cast<float4*>(out + base + 4) = o1;
    }
}

// dout=64: 8 neighbors/wave; 8 lanes x 4 half2 (16B) each; shfl_xor(8,16,32).
__global__ __launch_bounds__(256) void gather_d64_h(
    const float* __restrict__ h0, const __half2* __restrict__ h1,
    const int* __restrict__ rowptr, const int* __restrict__ adj,
    const float* __restrict__ dinv, float* __restrict__ out)
{
    const int v = blockIdx.x * 4 + (threadIdx.x >> 6);
    if (v >= NV) return;
    const int lane = threadIdx.x & 63;
    const int sub = lane >> 3;             // 0..7
    const int cu = (lane & 7) * 4;         // half2 column
    const int s = rowptr[v], e = rowptr[v + 1];

    float acc[8] = {};

    int j = s;
    const int jend = s + ((e - s) & ~15);
    for (; j < jend; j += 16) {
        const int4 w0 = *reinterpret_cast<const int4*>(h1 + (size_t)adj[j + sub] * 32 + cu);
        const int4 w1 = *reinterpret_cast<const int4*>(h1 + (size_t)adj[j + 8 + sub] * 32 + cu);
        #pragma unroll
        for (int t = 0; t < 4; ++t) {
            const float2 p = __half22float2(*(const __half2*)(&(&w0.x)[t]));
            const float2 q = __half22float2(*(const __half2*)(&(&w1.x)[t]));
            acc[2 * t + 0] += p.x + q.x;
            acc[2 * t + 1] += p.y + q.y;
        }
    }
    for (; j < e; j += 8) {
        const int jj = j + sub;
        if (jj < e) {
            const int4 w0 = *reinterpret_cast<const int4*>(h1 + (size_t)adj[jj] * 32 + cu);
            #pragma unroll
            for (int t = 0; t < 4; ++t) {
                const float2 p = __half22float2(*(const __half2*)(&(&w0.x)[t]));
                acc[2 * t + 0] += p.x;
                acc[2 * t + 1] += p.y;
            }
        }
    }

    #pragma unroll
    for (int t = 0; t < 8; ++t) {
        acc[t] += __shfl_xor(acc[t], 8);
        acc[t] += __shfl_xor(acc[t], 16);
        acc[t] += __shfl_xor(acc[t], 32);
    }

    if (sub == 0) {
        const float di = dinv[v];
        const size_t base = (size_t)v * 64 + (size_t)cu * 2;
        float4 o0, o1;
        o0.x = fmaxf((h0[base + 0] + acc[0]) * di, 0.f);
        o0.y = fmaxf((h0[base + 1] + acc[1]) * di, 0.f);
        o0.z = fmaxf((h0[base + 2] + acc[2]) * di, 0.f);
        o0.w = fmaxf((h0[base + 3] + acc[3]) * di, 0.f);
        o1.x = fmaxf((h0[base + 4] + acc[4]) * di, 0.f);
        o1.y = fmaxf((h0[base + 5] + acc[5]) * di, 0.f);
        o1.z = fmaxf((h0[base + 6] + acc[6]) * di, 0.f);
        o1.w = fmaxf((h0[base + 7] + acc[7]) * di, 0.f);
        *reinterpret_cast<float4*>(out + base + 0) = o0;
        *reinterpret_cast<float4*>(out + base + 4) = o1;
    }
}

// dout=3 (last layer, fp32 h1, no relu): lane-per-neighbor, butterfly reduce
__global__ __launch_bounds__(256) void gather_d3(
    const float* __restrict__ h0, const float* __restrict__ h1,
    const int* __restrict__ rowptr, const int* __restrict__ adj,
    const float* __restrict__ dinv, float* __restrict__ out)
{
    const int v = blockIdx.x * 4 + (threadIdx.x >> 6);
    if (v >= NV) return;
    const int lane = threadIdx.x & 63;
    const int s = rowptr[v], e = rowptr[v + 1];
    float a0 = 0.f, a1 = 0.f, a2 = 0.f;
    for (int j = s + lane; j < e; j += 64) {
        const float3 r = *reinterpret_cast<const float3*>(h1 + (size_t)adj[j] * 3);
        a0 += r.x; a1 += r.y; a2 += r.z;
    }
    #pragma unroll
    for (int off = 1; off < 64; off <<= 1) {
        a0 += __shfl_xor(a0, off);
        a1 += __shfl_xor(a1, off);
        a2 += __shfl_xor(a2, off);
    }
    if (lane == 0) {
        const float di = dinv[v];
        const size_t base = (size_t)v * 3;
        out[base + 0] = (h0[base + 0] + a0) * di;
        out[base + 1] = (h0[base + 1] + a1) * di;
        out[base + 2] = (h0[base + 2] + a2) * di;
    }
}

extern "C" void kernel_launch(void* const* d_in, const int* in_sizes, int n_in,
                              void* d_out, int out_size, void* d_ws, size_t ws_size,
                              hipStream_t stream) {
    const float* features = (const float*)d_in[0];
    const int*   edges    = (const int*)d_in[1];

    char* ws = (char*)d_ws;
    size_t off = 0;
    auto alloc = [&](size_t bytes) {
        void* p = ws + off;
        off = (off + bytes + 255) & ~(size_t)255;
        return p;
    };
    int*   deg    = (int*)alloc((size_t)NV * sizeof(int));
    float* dinv   = (float*)alloc((size_t)NV * sizeof(float));
    int*   rowptr = (int*)alloc((size_t)(NV + 1) * sizeof(int));
    int*   fill   = (int*)alloc((size_t)NV * sizeof(int));
    int*   bsum   = (int*)alloc(256 * sizeof(int));
    int*   adj    = (int*)alloc((size_t)2 * NE * sizeof(int));
    float* buf0   = (float*)alloc((size_t)NV * 192 * sizeof(float));   // C0 / x
    void*  buf1   = alloc((size_t)NV * 192 * sizeof(float));           // C1 (fp16 or fp32)
    float* buf2   = (float*)alloc((size_t)NV * 128 * sizeof(float));   // C0 / x

    // ---- CSR build ----
    hipMemsetAsync(deg, 0, (size_t)NV * sizeof(int), stream);
    degree_count<<<(2 * NE + 255) / 256, 256, 0, stream>>>(edges, deg, 2 * NE);
    scan_block<<<NBLK, SCAN_B, 0, stream>>>(deg, rowptr, bsum, NV);
    scan_top<<<1, 128, 0, stream>>>(bsum, NBLK);
    finalize_rowptr<<<NBLK, SCAN_B, 0, stream>>>(rowptr, bsum, deg, fill, dinv, NV);
    fill_adj<<<(NE + 255) / 256, 256, 0, stream>>>(edges, fill, adj, NE);

    // ---- layers ----
    const int dims[5] = {256, 192, 128, 64, 3};
    const float* Xp[4];
    float* C0p[4];
    Xp[0] = features; C0p[0] = buf0;
    Xp[1] = buf0;     C0p[1] = buf2;
    Xp[2] = buf2;     C0p[2] = buf0;
    Xp[3] = buf0;     C0p[3] = buf2;

    const int gatherGrid = (NV + 3) / 4;

    for (int li = 0; li < 4; ++li) {
        const int din  = dims[li];
        const int dout = dims[li + 1];
        const float* W0 = (const float*)d_in[2 + li * 4 + 0];
        const float* b0 = (const float*)d_in[2 + li * 4 + 1];
        const float* W1 = (const float*)d_in[2 + li * 4 + 2];
        const float* b1 = (const float*)d_in[2 + li * 4 + 3];

        dim3 grid((NV + BM - 1) / BM, (dout + BN - 1) / BN);
        if (li < 3)
            gemm_dual_bias<true><<<grid, 256, 0, stream>>>(Xp[li], W0, b0, W1, b1,
                                                           C0p[li], buf1, NV, din, dout);
        else
            gemm_dual_bias<false><<<grid, 256, 0, stream>>>(Xp[li], W0, b0, W1, b1,
                                                            C0p[li], buf1, NV, din, dout);

        float* dst = (li < 3) ? C0p[li] : (float*)d_out;
        if (li == 0)
            gather_d192_h<<<gatherGrid, 256, 0, stream>>>(C0p[li], (const __half2*)buf1,
                                                          rowptr, adj, dinv, dst);
        else if (li == 1)
            gather_d128_h<<<gatherGrid, 256, 0, stream>>>(C0p[li], (const __half2*)buf1,
                                                          rowptr, adj, dinv, dst);
        else if (li == 2)
            gather_d64_h<<<gatherGrid, 256, 0, stream>>>(C0p[li], (const __half2*)buf1,
                                                         rowptr, adj, dinv, dst);
        else
            gather_d3<<<gatherGrid, 256, 0, stream>>>(C0p[li], (const float*)buf1,
                                                      rowptr, adj, dinv, dst);
    }
}

// Round 5
// 806.483 us; speedup vs baseline: 5.9488x; 1.3414x over previous
//
#include <hip/hip_runtime.h>
#include <hip/hip_fp16.h>

#define NV 100000
#define NE 1600000

#define BM 64
#define BN 64
#define BK 16

#define TBM 128
#define TBN 64
#define TBK 32
#define APAD 40
#define BPAD 40

#define SCAN_B 1024
#define NBLK ((NV + SCAN_B - 1) / SCAN_B)   // 98

typedef __attribute__((ext_vector_type(8))) _Float16 f16x8;
typedef __attribute__((ext_vector_type(4))) _Float16 f16x4;
typedef __attribute__((ext_vector_type(4))) float f32x4;

// ---------------- degree histogram ----------------
__global__ void degree_count(const int* __restrict__ ef, int* __restrict__ deg, int n) {
    int i = blockIdx.x * blockDim.x + threadIdx.x;
    if (i < n) atomicAdd(&deg[ef[i]], 1);
}

// ---------------- block-level exclusive scan ----------------
__global__ __launch_bounds__(SCAN_B) void scan_block(const int* __restrict__ deg,
                                                     int* __restrict__ part,
                                                     int* __restrict__ bsum, int n) {
    __shared__ int tmp[SCAN_B];
    const int tid = threadIdx.x;
    const int gid = blockIdx.x * SCAN_B + tid;
    int v = (gid < n) ? deg[gid] : 0;
    tmp[tid] = v;
    __syncthreads();
    for (int off = 1; off < SCAN_B; off <<= 1) {
        int t = (tid >= off) ? tmp[tid - off] : 0;
        __syncthreads();
        tmp[tid] += t;
        __syncthreads();
    }
    if (gid < n) part[gid] = tmp[tid] - v;       // exclusive
    if (tid == SCAN_B - 1) bsum[blockIdx.x] = tmp[tid];
}

__global__ __launch_bounds__(128) void scan_top(int* __restrict__ bsum, int nb) {
    __shared__ int tmp[128];
    const int tid = threadIdx.x;
    int v = (tid < nb) ? bsum[tid] : 0;
    tmp[tid] = v;
    __syncthreads();
    for (int off = 1; off < 128; off <<= 1) {
        int t = (tid >= off) ? tmp[tid - off] : 0;
        __syncthreads();
        tmp[tid] += t;
        __syncthreads();
    }
    if (tid < nb) bsum[tid] = tmp[tid] - v;      // exclusive
}

__global__ __launch_bounds__(SCAN_B) void finalize_rowptr(int* __restrict__ rowptr,
                                                          const int* __restrict__ bsum,
                                                          const int* __restrict__ deg,
                                                          int* __restrict__ fill,
                                                          float* __restrict__ dinv, int n) {
    const int gid = blockIdx.x * SCAN_B + threadIdx.x;
    if (gid < n) {
        int r = rowptr[gid] + bsum[blockIdx.x];
        rowptr[gid] = r;
        fill[gid] = r;
        dinv[gid] = 1.0f / (float)deg[gid];
    }
    if (gid == 0) rowptr[n] = 2 * NE;
}

__global__ void fill_adj(const int* __restrict__ edges, int* __restrict__ fill,
                         int* __restrict__ adj, int nE) {
    int e = blockIdx.x * blockDim.x + threadIdx.x;
    if (e >= nE) return;
    const int a = edges[2 * e];
    const int b = edges[2 * e + 1];
    int pa = atomicAdd(&fill[a], 1); adj[pa] = b;
    int pb = atomicAdd(&fill[b], 1); adj[pb] = a;
}

// ---------------- MFMA dual GEMM: C0 = X@W0+b0 (fp32), C1 = X@W1+b1 (fp16) ----------------
// 128x64 tile, 4 waves (2x2), each wave 64x32 via 4x2 fragments of 16x16x32, dual B.
// Requires din % 32 == 0, dout % 64 == 0.
__global__ __launch_bounds__(256) void gemm_dual_mfma(
    const float* __restrict__ X,
    const float* __restrict__ W0, const float* __restrict__ b0,
    const float* __restrict__ W1, const float* __restrict__ b1,
    float* __restrict__ C0, _Float16* __restrict__ C1,
    int M, int din, int dout)
{
    __shared__ _Float16 As[TBM * APAD];        // 10 KB
    __shared__ _Float16 Bs[2][TBN * BPAD];     // 10 KB

    const int tid = threadIdx.x;
    const int bm = blockIdx.x * TBM;
    const int bn = blockIdx.y * TBN;
    const int lane = tid & 63;
    const int wid = tid >> 6;
    const int wm = wid >> 1;       // 0..1
    const int wn = wid & 1;        // 0..1
    const int lr = lane & 15;      // fragment row/col
    const int lk = lane >> 4;      // k-group 0..3

    f32x4 acc[2][4][2] = {};       // [out][mfrag][nfrag]

    const int bn_n = tid & 63;            // B staging: column
    const int bn_kb = (tid >> 6) * 8;     // B staging: k base (8 per wave)

    for (int k0 = 0; k0 < din; k0 += TBK) {
        // ---- stage A: [128][32] fp32 -> fp16, padded rows ----
        #pragma unroll
        for (int i = 0; i < 4; ++i) {
            const int idx = tid + i * 256;          // < 1024
            const int row = idx >> 3;
            const int q = idx & 7;
            const int grow = bm + row;
            float4 v = {0.f, 0.f, 0.f, 0.f};
            if (grow < M)
                v = *reinterpret_cast<const float4*>(&X[(size_t)grow * din + k0 + q * 4]);
            f16x4 h = { (_Float16)v.x, (_Float16)v.y, (_Float16)v.z, (_Float16)v.w };
            *reinterpret_cast<f16x4*>(&As[row * APAD + q * 4]) = h;
        }
        // ---- stage B0/B1 transposed: Bs[o][n][k] ----
        {
            const float* pw0 = &W0[(size_t)(k0 + bn_kb) * dout + bn + bn_n];
            const float* pw1 = &W1[(size_t)(k0 + bn_kb) * dout + bn + bn_n];
            _Float16* d0 = &Bs[0][bn_n * BPAD + bn_kb];
            _Float16* d1 = &Bs[1][bn_n * BPAD + bn_kb];
            #pragma unroll
            for (int i = 0; i < 8; ++i) {
                d0[i] = (_Float16)pw0[(size_t)i * dout];
                d1[i] = (_Float16)pw1[(size_t)i * dout];
            }
        }
        __syncthreads();

        // ---- fragments + MFMA ----
        f16x8 a[4], b[2][2];
        #pragma unroll
        for (int mf = 0; mf < 4; ++mf)
            a[mf] = *reinterpret_cast<const f16x8*>(&As[(wm * 64 + mf * 16 + lr) * APAD + lk * 8]);
        #pragma unroll
        for (int o = 0; o < 2; ++o)
            #pragma unroll
            for (int nf = 0; nf < 2; ++nf)
                b[o][nf] = *reinterpret_cast<const f16x8*>(&Bs[o][(wn * 32 + nf * 16 + lr) * BPAD + lk * 8]);

        #pragma unroll
        for (int o = 0; o < 2; ++o)
            #pragma unroll
            for (int mf = 0; mf < 4; ++mf)
                #pragma unroll
                for (int nf = 0; nf < 2; ++nf)
                    acc[o][mf][nf] = __builtin_amdgcn_mfma_f32_16x16x32_f16(
                        a[mf], b[o][nf], acc[o][mf][nf], 0, 0, 0);

        __syncthreads();
    }

    // ---- epilogue: C/D layout col=lane&15, row=(lane>>4)*4+reg ----
    #pragma unroll
    for (int mf = 0; mf < 4; ++mf) {
        #pragma unroll
        for (int reg = 0; reg < 4; ++reg) {
            const int row = bm + wm * 64 + mf * 16 + lk * 4 + reg;
            if (row >= M) continue;
            #pragma unroll
            for (int nf = 0; nf < 2; ++nf) {
                const int c = bn + wn * 32 + nf * 16 + lr;
                C0[(size_t)row * dout + c] = acc[0][mf][nf][reg] + b0[c];
                C1[(size_t)row * dout + c] = (_Float16)(acc[1][mf][nf][reg] + b1[c]);
            }
        }
    }
}

// ---------------- vector dual GEMM (layer 3 only: dout=3) ----------------
__global__ __launch_bounds__(256) void gemm_dual_bias_f32(
    const float* __restrict__ X,
    const float* __restrict__ W0, const float* __restrict__ b0,
    const float* __restrict__ W1, const float* __restrict__ b1,
    float* __restrict__ C0, float* __restrict__ C1,
    int M, int din, int dout)
{
    __shared__ float As[BM][BK + 1];
    __shared__ float Bs0[BK][BN];
    __shared__ float Bs1[BK][BN];

    const int tid = threadIdx.x;
    const int bm = blockIdx.x * BM;
    const int bn = blockIdx.y * BN;
    const int tx = tid & 15;
    const int ty = tid >> 4;

    const int ar = tid >> 2;
    const int ac = (tid & 3) * 4;
    const int br = tid >> 4;
    const int bc = (tid & 15) * 4;

    float acc0[4][4] = {};
    float acc1[4][4] = {};

    for (int k0 = 0; k0 < din; k0 += BK) {
        {
            const int grow = bm + ar;
            if (grow < M) {
                const float4 v = *reinterpret_cast<const float4*>(&X[(size_t)grow * din + k0 + ac]);
                As[ar][ac + 0] = v.x; As[ar][ac + 1] = v.y;
                As[ar][ac + 2] = v.z; As[ar][ac + 3] = v.w;
            } else {
                As[ar][ac + 0] = 0.f; As[ar][ac + 1] = 0.f;
                As[ar][ac + 2] = 0.f; As[ar][ac + 3] = 0.f;
            }
        }
        {
            const int gk = k0 + br;
            const int gc = bn + bc;
            float4 v0, v1;
            v0.x = (gc + 0 < dout) ? W0[(size_t)gk * dout + gc + 0] : 0.f;
            v0.y = (gc + 1 < dout) ? W0[(size_t)gk * dout + gc + 1] : 0.f;
            v0.z = (gc + 2 < dout) ? W0[(size_t)gk * dout + gc + 2] : 0.f;
            v0.w = (gc + 3 < dout) ? W0[(size_t)gk * dout + gc + 3] : 0.f;
            v1.x = (gc + 0 < dout) ? W1[(size_t)gk * dout + gc + 0] : 0.f;
            v1.y = (gc + 1 < dout) ? W1[(size_t)gk * dout + gc + 1] : 0.f;
            v1.z = (gc + 2 < dout) ? W1[(size_t)gk * dout + gc + 2] : 0.f;
            v1.w = (gc + 3 < dout) ? W1[(size_t)gk * dout + gc + 3] : 0.f;
            *reinterpret_cast<float4*>(&Bs0[br][bc]) = v0;
            *reinterpret_cast<float4*>(&Bs1[br][bc]) = v1;
        }
        __syncthreads();

        #pragma unroll
        for (int kk = 0; kk < BK; ++kk) {
            const float a0 = As[ty * 4 + 0][kk];
            const float a1 = As[ty * 4 + 1][kk];
            const float a2 = As[ty * 4 + 2][kk];
            const float a3 = As[ty * 4 + 3][kk];
            const float4 p = *reinterpret_cast<const float4*>(&Bs0[kk][tx * 4]);
            const float4 q = *reinterpret_cast<const float4*>(&Bs1[kk][tx * 4]);
            acc0[0][0] += a0 * p.x; acc0[0][1] += a0 * p.y; acc0[0][2] += a0 * p.z; acc0[0][3] += a0 * p.w;
            acc0[1][0] += a1 * p.x; acc0[1][1] += a1 * p.y; acc0[1][2] += a1 * p.z; acc0[1][3] += a1 * p.w;
            acc0[2][0] += a2 * p.x; acc0[2][1] += a2 * p.y; acc0[2][2] += a2 * p.z; acc0[2][3] += a2 * p.w;
            acc0[3][0] += a3 * p.x; acc0[3][1] += a3 * p.y; acc0[3][2] += a3 * p.z; acc0[3][3] += a3 * p.w;
            acc1[0][0] += a0 * q.x; acc1[0][1] += a0 * q.y; acc1[0][2] += a0 * q.z; acc1[0][3] += a0 * q.w;
            acc1[1][0] += a1 * q.x; acc1[1][1] += a1 * q.y; acc1[1][2] += a1 * q.z; acc1[1][3] += a1 * q.w;
            acc1[2][0] += a2 * q.x; acc1[2][1] += a2 * q.y; acc1[2][2] += a2 * q.z; acc1[2][3] += a2 * q.w;
            acc1[3][0] += a3 * q.x; acc1[3][1] += a3 * q.y; acc1[3][2] += a3 * q.z; acc1[3][3] += a3 * q.w;
        }
        __syncthreads();
    }

    #pragma unroll
    for (int i = 0; i < 4; ++i) {
        const int row = bm + ty * 4 + i;
        if (row >= M) continue;
        #pragma unroll
        for (int j = 0; j < 4; ++j) {
            const int col = bn + tx * 4 + j;
            if (col < dout) {
                C0[(size_t)row * dout + col] = acc0[i][j] + b0[col];
                C1[(size_t)row * dout + col] = acc1[i][j] + b1[col];
            }
        }
    }
}

// ---------------- gathers over fp16 h1 ----------------
__global__ __launch_bounds__(256) void gather_d192_h(
    const float* __restrict__ h0, const __half2* __restrict__ h1,
    const int* __restrict__ rowptr, const int* __restrict__ adj,
    const float* __restrict__ dinv, float* __restrict__ out)
{
    const int v = blockIdx.x * 4 + (threadIdx.x >> 6);
    if (v >= NV) return;
    const int lane = threadIdx.x & 63;
    const int sub = lane >> 5;
    const int cu = (lane & 31) * 3;
    const int s = rowptr[v], e = rowptr[v + 1];

    float2 a0 = {0.f, 0.f}, a1 = {0.f, 0.f}, a2 = {0.f, 0.f};

    int j = s;
    const int jend = s + ((e - s) & ~3);
    for (; j < jend; j += 4) {
        const __half2* r0 = h1 + (size_t)adj[j + sub] * 96 + cu;
        const __half2* r1 = h1 + (size_t)adj[j + 2 + sub] * 96 + cu;
        const float2 p0 = __half22float2(r0[0]);
        const float2 p1 = __half22float2(r0[1]);
        const float2 p2 = __half22float2(r0[2]);
        const float2 q0 = __half22float2(r1[0]);
        const float2 q1 = __half22float2(r1[1]);
        const float2 q2 = __half22float2(r1[2]);
        a0.x += p0.x + q0.x; a0.y += p0.y + q0.y;
        a1.x += p1.x + q1.x; a1.y += p1.y + q1.y;
        a2.x += p2.x + q2.x; a2.y += p2.y + q2.y;
    }
    for (; j < e; j += 2) {
        const int jj = j + sub;
        if (jj < e) {
            const __half2* r = h1 + (size_t)adj[jj] * 96 + cu;
            const float2 p0 = __half22float2(r[0]);
            const float2 p1 = __half22float2(r[1]);
            const float2 p2 = __half22float2(r[2]);
            a0.x += p0.x; a0.y += p0.y;
            a1.x += p1.x; a1.y += p1.y;
            a2.x += p2.x; a2.y += p2.y;
        }
    }

    a0.x += __shfl_xor(a0.x, 32); a0.y += __shfl_xor(a0.y, 32);
    a1.x += __shfl_xor(a1.x, 32); a1.y += __shfl_xor(a1.y, 32);
    a2.x += __shfl_xor(a2.x, 32); a2.y += __shfl_xor(a2.y, 32);

    if (sub == 0) {
        const float di = dinv[v];
        const size_t base = (size_t)v * 192 + (size_t)cu * 2;
        float2 o0, o1, o2;
        o0.x = fmaxf((h0[base + 0] + a0.x) * di, 0.f);
        o0.y = fmaxf((h0[base + 1] + a0.y) * di, 0.f);
        o1.x = fmaxf((h0[base + 2] + a1.x) * di, 0.f);
        o1.y = fmaxf((h0[base + 3] + a1.y) * di, 0.f);
        o2.x = fmaxf((h0[base + 4] + a2.x) * di, 0.f);
        o2.y = fmaxf((h0[base + 5] + a2.y) * di, 0.f);
        *reinterpret_cast<float2*>(out + base + 0) = o0;
        *reinterpret_cast<float2*>(out + base + 2) = o1;
        *reinterpret_cast<float2*>(out + base + 4) = o2;
    }
}

__global__ __launch_bounds__(256) void gather_d128_h(
    const float* __restrict__ h0, const __half2* __restrict__ h1,
    const int* __restrict__ rowptr, const int* __restrict__ adj,
    const float* __restrict__ dinv, float* __restrict__ out)
{
    const int v = blockIdx.x * 4 + (threadIdx.x >> 6);
    if (v >= NV) return;
    const int lane = threadIdx.x & 63;
    const int sub = lane >> 4;
    const int cu = (lane & 15) * 4;
    const int s = rowptr[v], e = rowptr[v + 1];

    float acc[8] = {};

    int j = s;
    const int jend = s + ((e - s) & ~7);
    for (; j < jend; j += 8) {
        const int4 w0 = *reinterpret_cast<const int4*>(h1 + (size_t)adj[j + sub] * 64 + cu);
        const int4 w1 = *reinterpret_cast<const int4*>(h1 + (size_t)adj[j + 4 + sub] * 64 + cu);
        #pragma unroll
        for (int t = 0; t < 4; ++t) {
            const float2 p = __half22float2(*(const __half2*)(&(&w0.x)[t]));
            const float2 q = __half22float2(*(const __half2*)(&(&w1.x)[t]));
            acc[2 * t + 0] += p.x + q.x;
            acc[2 * t + 1] += p.y + q.y;
        }
    }
    for (; j < e; j += 4) {
        const int jj = j + sub;
        if (jj < e) {
            const int4 w0 = *reinterpret_cast<const int4*>(h1 + (size_t)adj[jj] * 64 + cu);
            #pragma unroll
            for (int t = 0; t < 4; ++t) {
                const float2 p = __half22float2(*(const __half2*)(&(&w0.x)[t]));
                acc[2 * t + 0] += p.x;
                acc[2 * t + 1] += p.y;
            }
        }
    }

    #pragma unroll
    for (int t = 0; t < 8; ++t) {
        acc[t] += __shfl_xor(acc[t], 16);
        acc[t] += __shfl_xor(acc[t], 32);
    }

    if (sub == 0) {
        const float di = dinv[v];
        const size_t base = (size_t)v * 128 + (size_t)cu * 2;
        float4 o0, o1;
        o0.x = fmaxf((h0[base + 0] + acc[0]) * di, 0.f);
        o0.y = fmaxf((h0[base + 1] + acc[1]) * di, 0.f);
        o0.z = fmaxf((h0[base + 2] + acc[2]) * di, 0.f);
        o0.w = fmaxf((h0[base + 3] + acc[3]) * di, 0.f);
        o1.x = fmaxf((h0[base + 4] + acc[4]) * di, 0.f);
        o1.y = fmaxf((h0[base + 5] + acc[5]) * di, 0.f);
        o1.z = fmaxf((h0[base + 6] + acc[6]) * di, 0.f);
        o1.w = fmaxf((h0[base + 7] + acc[7]) * di, 0.f);
        *reinterpret_cast<float4*>(out + base + 0) = o0;
        *reinterpret_cast<float4*>(out + base + 4) = o1;
    }
}

__global__ __launch_bounds__(256) void gather_d64_h(
    const float* __restrict__ h0, const __half2* __restrict__ h1,
    const int* __restrict__ rowptr, const int* __restrict__ adj,
    const float* __restrict__ dinv, float* __restrict__ out)
{
    const int v = blockIdx.x * 4 + (threadIdx.x >> 6);
    if (v >= NV) return;
    const int lane = threadIdx.x & 63;
    const int sub = lane >> 3;
    const int cu = (lane & 7) * 4;
    const int s = rowptr[v], e = rowptr[v + 1];

    float acc[8] = {};

    int j = s;
    const int jend = s + ((e - s) & ~15);
    for (; j < jend; j += 16) {
        const int4 w0 = *reinterpret_cast<const int4*>(h1 + (size_t)adj[j + sub] * 32 + cu);
        const int4 w1 = *reinterpret_cast<const int4*>(h1 + (size_t)adj[j + 8 + sub] * 32 + cu);
        #pragma unroll
        for (int t = 0; t < 4; ++t) {
            const float2 p = __half22float2(*(const __half2*)(&(&w0.x)[t]));
            const float2 q = __half22float2(*(const __half2*)(&(&w1.x)[t]));
            acc[2 * t + 0] += p.x + q.x;
            acc[2 * t + 1] += p.y + q.y;
        }
    }
    for (; j < e; j += 8) {
        const int jj = j + sub;
        if (jj < e) {
            const int4 w0 = *reinterpret_cast<const int4*>(h1 + (size_t)adj[jj] * 32 + cu);
            #pragma unroll
            for (int t = 0; t < 4; ++t) {
                const float2 p = __half22float2(*(const __half2*)(&(&w0.x)[t]));
                acc[2 * t + 0] += p.x;
                acc[2 * t + 1] += p.y;
            }
        }
    }

    #pragma unroll
    for (int t = 0; t < 8; ++t) {
        acc[t] += __shfl_xor(acc[t], 8);
        acc[t] += __shfl_xor(acc[t], 16);
        acc[t] += __shfl_xor(acc[t], 32);
    }

    if (sub == 0) {
        const float di = dinv[v];
        const size_t base = (size_t)v * 64 + (size_t)cu * 2;
        float4 o0, o1;
        o0.x = fmaxf((h0[base + 0] + acc[0]) * di, 0.f);
        o0.y = fmaxf((h0[base + 1] + acc[1]) * di, 0.f);
        o0.z = fmaxf((h0[base + 2] + acc[2]) * di, 0.f);
        o0.w = fmaxf((h0[base + 3] + acc[3]) * di, 0.f);
        o1.x = fmaxf((h0[base + 4] + acc[4]) * di, 0.f);
        o1.y = fmaxf((h0[base + 5] + acc[5]) * di, 0.f);
        o1.z = fmaxf((h0[base + 6] + acc[6]) * di, 0.f);
        o1.w = fmaxf((h0[base + 7] + acc[7]) * di, 0.f);
        *reinterpret_cast<float4*>(out + base + 0) = o0;
        *reinterpret_cast<float4*>(out + base + 4) = o1;
    }
}

__global__ __launch_bounds__(256) void gather_d3(
    const float* __restrict__ h0, const float* __restrict__ h1,
    const int* __restrict__ rowptr, const int* __restrict__ adj,
    const float* __restrict__ dinv, float* __restrict__ out)
{
    const int v = blockIdx.x * 4 + (threadIdx.x >> 6);
    if (v >= NV) return;
    const int lane = threadIdx.x & 63;
    const int s = rowptr[v], e = rowptr[v + 1];
    float a0 = 0.f, a1 = 0.f, a2 = 0.f;
    for (int j = s + lane; j < e; j += 64) {
        const float3 r = *reinterpret_cast<const float3*>(h1 + (size_t)adj[j] * 3);
        a0 += r.x; a1 += r.y; a2 += r.z;
    }
    #pragma unroll
    for (int off = 1; off < 64; off <<= 1) {
        a0 += __shfl_xor(a0, off);
        a1 += __shfl_xor(a1, off);
        a2 += __shfl_xor(a2, off);
    }
    if (lane == 0) {
        const float di = dinv[v];
        const size_t base = (size_t)v * 3;
        out[base + 0] = (h0[base + 0] + a0) * di;
        out[base + 1] = (h0[base + 1] + a1) * di;
        out[base + 2] = (h0[base + 2] + a2) * di;
    }
}

extern "C" void kernel_launch(void* const* d_in, const int* in_sizes, int n_in,
                              void* d_out, int out_size, void* d_ws, size_t ws_size,
                              hipStream_t stream) {
    const float* features = (const float*)d_in[0];
    const int*   edges    = (const int*)d_in[1];

    char* ws = (char*)d_ws;
    size_t off = 0;
    auto alloc = [&](size_t bytes) {
        void* p = ws + off;
        off = (off + bytes + 255) & ~(size_t)255;
        return p;
    };
    int*   deg    = (int*)alloc((size_t)NV * sizeof(int));
    float* dinv   = (float*)alloc((size_t)NV * sizeof(float));
    int*   rowptr = (int*)alloc((size_t)(NV + 1) * sizeof(int));
    int*   fill   = (int*)alloc((size_t)NV * sizeof(int));
    int*   bsum   = (int*)alloc(256 * sizeof(int));
    int*   adj    = (int*)alloc((size_t)2 * NE * sizeof(int));
    float* buf0   = (float*)alloc((size_t)NV * 192 * sizeof(float));   // C0 / x
    void*  buf1   = alloc((size_t)NV * 192 * sizeof(float));           // C1 (fp16 or fp32)
    float* buf2   = (float*)alloc((size_t)NV * 128 * sizeof(float));   // C0 / x

    // ---- CSR build ----
    hipMemsetAsync(deg, 0, (size_t)NV * sizeof(int), stream);
    degree_count<<<(2 * NE + 255) / 256, 256, 0, stream>>>(edges, deg, 2 * NE);
    scan_block<<<NBLK, SCAN_B, 0, stream>>>(deg, rowptr, bsum, NV);
    scan_top<<<1, 128, 0, stream>>>(bsum, NBLK);
    finalize_rowptr<<<NBLK, SCAN_B, 0, stream>>>(rowptr, bsum, deg, fill, dinv, NV);
    fill_adj<<<(NE + 255) / 256, 256, 0, stream>>>(edges, fill, adj, NE);

    // ---- layers ----
    const int dims[5] = {256, 192, 128, 64, 3};
    const float* Xp[4];
    float* C0p[4];
    Xp[0] = features; C0p[0] = buf0;
    Xp[1] = buf0;     C0p[1] = buf2;
    Xp[2] = buf2;     C0p[2] = buf0;
    Xp[3] = buf0;     C0p[3] = buf2;

    const int gatherGrid = (NV + 3) / 4;

    for (int li = 0; li < 4; ++li) {
        const int din  = dims[li];
        const int dout = dims[li + 1];
        const float* W0 = (const float*)d_in[2 + li * 4 + 0];
        const float* b0 = (const float*)d_in[2 + li * 4 + 1];
        const float* W1 = (const float*)d_in[2 + li * 4 + 2];
        const float* b1 = (const float*)d_in[2 + li * 4 + 3];

        if (li < 3) {
            dim3 grid((NV + TBM - 1) / TBM, dout / TBN);
            gemm_dual_mfma<<<grid, 256, 0, stream>>>(Xp[li], W0, b0, W1, b1,
                                                     C0p[li], (_Float16*)buf1, NV, din, dout);
        } else {
            dim3 grid((NV + BM - 1) / BM, (dout + BN - 1) / BN);
            gemm_dual_bias_f32<<<grid, 256, 0, stream>>>(Xp[li], W0, b0, W1, b1,
                                                         C0p[li], (float*)buf1, NV, din, dout);
        }

        float* dst = (li < 3) ? C0p[li] : (float*)d_out;
        if (li == 0)
            gather_d192_h<<<gatherGrid, 256, 0, stream>>>(C0p[li], (const __half2*)buf1,
                                                          rowptr, adj, dinv, dst);
        else if (li == 1)
            gather_d128_h<<<gatherGrid, 256, 0, stream>>>(C0p[li], (const __half2*)buf1,
                                                          rowptr, adj, dinv, dst);
        else if (li == 2)
            gather_d64_h<<<gatherGrid, 256, 0, stream>>>(C0p[li], (const __half2*)buf1,
                                                         rowptr, adj, dinv, dst);
        else
            gather_d3<<<gatherGrid, 256, 0, stream>>>(C0p[li], (const float*)buf1,
                                                      rowptr, adj, dinv, dst);
    }
}

// Round 6
// 786.175 us; speedup vs baseline: 6.1025x; 1.0258x over previous
//
#include <hip/hip_runtime.h>
#include <hip/hip_fp16.h>

#define NV 100000
#define NE 1600000

#define BM 64
#define BN 64
#define BK 16

#define TBM 128
#define TBN 64
#define TBK 32
#define APAD 40
#define BPAD 40

#define SCAN_B 1024
#define NBLK ((NV + SCAN_B - 1) / SCAN_B)   // 98

typedef __attribute__((ext_vector_type(8))) _Float16 f16x8;
typedef __attribute__((ext_vector_type(4))) _Float16 f16x4;
typedef __attribute__((ext_vector_type(2))) _Float16 f16x2;
typedef __attribute__((ext_vector_type(4))) float f32x4;

// ---------------- degree histogram ----------------
__global__ void degree_count(const int* __restrict__ ef, int* __restrict__ deg, int n) {
    int i = blockIdx.x * blockDim.x + threadIdx.x;
    if (i < n) atomicAdd(&deg[ef[i]], 1);
}

// ---------------- block-level exclusive scan ----------------
__global__ __launch_bounds__(SCAN_B) void scan_block(const int* __restrict__ deg,
                                                     int* __restrict__ part,
                                                     int* __restrict__ bsum, int n) {
    __shared__ int tmp[SCAN_B];
    const int tid = threadIdx.x;
    const int gid = blockIdx.x * SCAN_B + tid;
    int v = (gid < n) ? deg[gid] : 0;
    tmp[tid] = v;
    __syncthreads();
    for (int off = 1; off < SCAN_B; off <<= 1) {
        int t = (tid >= off) ? tmp[tid - off] : 0;
        __syncthreads();
        tmp[tid] += t;
        __syncthreads();
    }
    if (gid < n) part[gid] = tmp[tid] - v;       // exclusive
    if (tid == SCAN_B - 1) bsum[blockIdx.x] = tmp[tid];
}

__global__ __launch_bounds__(128) void scan_top(int* __restrict__ bsum, int nb) {
    __shared__ int tmp[128];
    const int tid = threadIdx.x;
    int v = (tid < nb) ? bsum[tid] : 0;
    tmp[tid] = v;
    __syncthreads();
    for (int off = 1; off < 128; off <<= 1) {
        int t = (tid >= off) ? tmp[tid - off] : 0;
        __syncthreads();
        tmp[tid] += t;
        __syncthreads();
    }
    if (tid < nb) bsum[tid] = tmp[tid] - v;      // exclusive
}

__global__ __launch_bounds__(SCAN_B) void finalize_rowptr(int* __restrict__ rowptr,
                                                          const int* __restrict__ bsum,
                                                          const int* __restrict__ deg,
                                                          int* __restrict__ fill,
                                                          float* __restrict__ dinv, int n) {
    const int gid = blockIdx.x * SCAN_B + threadIdx.x;
    if (gid < n) {
        int r = rowptr[gid] + bsum[blockIdx.x];
        rowptr[gid] = r;
        fill[gid] = r;
        dinv[gid] = 1.0f / (float)deg[gid];
    }
    if (gid == 0) rowptr[n] = 2 * NE;
}

__global__ void fill_adj(const int* __restrict__ edges, int* __restrict__ fill,
                         int* __restrict__ adj, int nE) {
    int e = blockIdx.x * blockDim.x + threadIdx.x;
    if (e >= nE) return;
    const int a = edges[2 * e];
    const int b = edges[2 * e + 1];
    int pa = atomicAdd(&fill[a], 1); adj[pa] = b;
    int pb = atomicAdd(&fill[b], 1); adj[pb] = a;
}

// ---------------- MFMA dual GEMM: C0 = X@W0+b0 (fp32), C1 = X@W1+b1 (fp16) ----------------
// 128x64 tile, 4 waves (2x2), each wave 64x32 via 4x2 fragments of 16x16x32, dual B.
// XT = float (layer 0) or _Float16 (layers 1+). Requires din % 32 == 0, dout % 64 == 0.
template <typename XT>
__global__ __launch_bounds__(256) void gemm_dual_mfma(
    const XT* __restrict__ X,
    const float* __restrict__ W0, const float* __restrict__ b0,
    const float* __restrict__ W1, const float* __restrict__ b1,
    float* __restrict__ C0, _Float16* __restrict__ C1,
    int M, int din, int dout)
{
    __shared__ _Float16 As[TBM * APAD];        // 10 KB
    __shared__ _Float16 Bs[2][TBN * BPAD];     // 10 KB

    const int tid = threadIdx.x;
    const int bm = blockIdx.x * TBM;
    const int bn = blockIdx.y * TBN;
    const int lane = tid & 63;
    const int wid = tid >> 6;
    const int wm = wid >> 1;       // 0..1
    const int wn = wid & 1;        // 0..1
    const int lr = lane & 15;      // fragment row/col
    const int lk = lane >> 4;      // k-group 0..3

    f32x4 acc[2][4][2] = {};       // [out][mfrag][nfrag]

    const int bn_n = tid & 63;            // B staging: column
    const int bn_kb = (tid >> 6) * 8;     // B staging: k base (8 per wave)

    for (int k0 = 0; k0 < din; k0 += TBK) {
        // ---- stage A ----
        if constexpr (sizeof(XT) == 4) {
            #pragma unroll
            for (int i = 0; i < 4; ++i) {
                const int idx = tid + i * 256;          // < 1024
                const int row = idx >> 3;
                const int q = idx & 7;
                const int grow = bm + row;
                float4 v = {0.f, 0.f, 0.f, 0.f};
                if (grow < M)
                    v = *reinterpret_cast<const float4*>(&X[(size_t)grow * din + k0 + q * 4]);
                f16x4 h = { (_Float16)v.x, (_Float16)v.y, (_Float16)v.z, (_Float16)v.w };
                *reinterpret_cast<f16x4*>(&As[row * APAD + q * 4]) = h;
            }
        } else {
            #pragma unroll
            for (int i = 0; i < 2; ++i) {
                const int idx = tid + i * 256;          // < 512
                const int row = idx >> 2;
                const int q = idx & 3;
                const int grow = bm + row;
                f16x8 h = {};
                if (grow < M)
                    h = *reinterpret_cast<const f16x8*>(&X[(size_t)grow * din + k0 + q * 8]);
                *reinterpret_cast<f16x8*>(&As[row * APAD + q * 8]) = h;
            }
        }
        // ---- stage B0/B1 transposed: Bs[o][n][k] ----
        {
            const float* pw0 = &W0[(size_t)(k0 + bn_kb) * dout + bn + bn_n];
            const float* pw1 = &W1[(size_t)(k0 + bn_kb) * dout + bn + bn_n];
            _Float16* d0 = &Bs[0][bn_n * BPAD + bn_kb];
            _Float16* d1 = &Bs[1][bn_n * BPAD + bn_kb];
            #pragma unroll
            for (int i = 0; i < 8; ++i) {
                d0[i] = (_Float16)pw0[(size_t)i * dout];
                d1[i] = (_Float16)pw1[(size_t)i * dout];
            }
        }
        __syncthreads();

        // ---- fragments + MFMA ----
        f16x8 a[4], b[2][2];
        #pragma unroll
        for (int mf = 0; mf < 4; ++mf)
            a[mf] = *reinterpret_cast<const f16x8*>(&As[(wm * 64 + mf * 16 + lr) * APAD + lk * 8]);
        #pragma unroll
        for (int o = 0; o < 2; ++o)
            #pragma unroll
            for (int nf = 0; nf < 2; ++nf)
                b[o][nf] = *reinterpret_cast<const f16x8*>(&Bs[o][(wn * 32 + nf * 16 + lr) * BPAD + lk * 8]);

        #pragma unroll
        for (int o = 0; o < 2; ++o)
            #pragma unroll
            for (int mf = 0; mf < 4; ++mf)
                #pragma unroll
                for (int nf = 0; nf < 2; ++nf)
                    acc[o][mf][nf] = __builtin_amdgcn_mfma_f32_16x16x32_f16(
                        a[mf], b[o][nf], acc[o][mf][nf], 0, 0, 0);

        __syncthreads();
    }

    // ---- epilogue: C/D layout col=lane&15, row=(lane>>4)*4+reg ----
    #pragma unroll
    for (int mf = 0; mf < 4; ++mf) {
        #pragma unroll
        for (int reg = 0; reg < 4; ++reg) {
            const int row = bm + wm * 64 + mf * 16 + lk * 4 + reg;
            if (row >= M) continue;
            #pragma unroll
            for (int nf = 0; nf < 2; ++nf) {
                const int c = bn + wn * 32 + nf * 16 + lr;
                C0[(size_t)row * dout + c] = acc[0][mf][nf][reg] + b0[c];
                C1[(size_t)row * dout + c] = (_Float16)(acc[1][mf][nf][reg] + b1[c]);
            }
        }
    }
}

// ---------------- vector dual GEMM (layer 3 only: dout=3, fp16 X) ----------------
__global__ __launch_bounds__(256) void gemm_dual_bias_f32(
    const _Float16* __restrict__ X,
    const float* __restrict__ W0, const float* __restrict__ b0,
    const float* __restrict__ W1, const float* __restrict__ b1,
    float* __restrict__ C0, float* __restrict__ C1,
    int M, int din, int dout)
{
    __shared__ float As[BM][BK + 1];
    __shared__ float Bs0[BK][BN];
    __shared__ float Bs1[BK][BN];

    const int tid = threadIdx.x;
    const int bm = blockIdx.x * BM;
    const int bn = blockIdx.y * BN;
    const int tx = tid & 15;
    const int ty = tid >> 4;

    const int ar = tid >> 2;
    const int ac = (tid & 3) * 4;
    const int br = tid >> 4;
    const int bc = (tid & 15) * 4;

    float acc0[4][4] = {};
    float acc1[4][4] = {};

    for (int k0 = 0; k0 < din; k0 += BK) {
        {
            const int grow = bm + ar;
            if (grow < M) {
                const f16x4 v = *reinterpret_cast<const f16x4*>(&X[(size_t)grow * din + k0 + ac]);
                As[ar][ac + 0] = (float)v[0]; As[ar][ac + 1] = (float)v[1];
                As[ar][ac + 2] = (float)v[2]; As[ar][ac + 3] = (float)v[3];
            } else {
                As[ar][ac + 0] = 0.f; As[ar][ac + 1] = 0.f;
                As[ar][ac + 2] = 0.f; As[ar][ac + 3] = 0.f;
            }
        }
        {
            const int gk = k0 + br;
            const int gc = bn + bc;
            float4 v0, v1;
            v0.x = (gc + 0 < dout) ? W0[(size_t)gk * dout + gc + 0] : 0.f;
            v0.y = (gc + 1 < dout) ? W0[(size_t)gk * dout + gc + 1] : 0.f;
            v0.z = (gc + 2 < dout) ? W0[(size_t)gk * dout + gc + 2] : 0.f;
            v0.w = (gc + 3 < dout) ? W0[(size_t)gk * dout + gc + 3] : 0.f;
            v1.x = (gc + 0 < dout) ? W1[(size_t)gk * dout + gc + 0] : 0.f;
            v1.y = (gc + 1 < dout) ? W1[(size_t)gk * dout + gc + 1] : 0.f;
            v1.z = (gc + 2 < dout) ? W1[(size_t)gk * dout + gc + 2] : 0.f;
            v1.w = (gc + 3 < dout) ? W1[(size_t)gk * dout + gc + 3] : 0.f;
            *reinterpret_cast<float4*>(&Bs0[br][bc]) = v0;
            *reinterpret_cast<float4*>(&Bs1[br][bc]) = v1;
        }
        __syncthreads();

        #pragma unroll
        for (int kk = 0; kk < BK; ++kk) {
            const float a0 = As[ty * 4 + 0][kk];
            const float a1 = As[ty * 4 + 1][kk];
            const float a2 = As[ty * 4 + 2][kk];
            const float a3 = As[ty * 4 + 3][kk];
            const float4 p = *reinterpret_cast<const float4*>(&Bs0[kk][tx * 4]);
            const float4 q = *reinterpret_cast<const float4*>(&Bs1[kk][tx * 4]);
            acc0[0][0] += a0 * p.x; acc0[0][1] += a0 * p.y; acc0[0][2] += a0 * p.z; acc0[0][3] += a0 * p.w;
            acc0[1][0] += a1 * p.x; acc0[1][1] += a1 * p.y; acc0[1][2] += a1 * p.z; acc0[1][3] += a1 * p.w;
            acc0[2][0] += a2 * p.x; acc0[2][1] += a2 * p.y; acc0[2][2] += a2 * p.z; acc0[2][3] += a2 * p.w;
            acc0[3][0] += a3 * p.x; acc0[3][1] += a3 * p.y; acc0[3][2] += a3 * p.z; acc0[3][3] += a3 * p.w;
            acc1[0][0] += a0 * q.x; acc1[0][1] += a0 * q.y; acc1[0][2] += a0 * q.z; acc1[0][3] += a0 * q.w;
            acc1[1][0] += a1 * q.x; acc1[1][1] += a1 * q.y; acc1[1][2] += a1 * q.z; acc1[1][3] += a1 * q.w;
            acc1[2][0] += a2 * q.x; acc1[2][1] += a2 * q.y; acc1[2][2] += a2 * q.z; acc1[2][3] += a2 * q.w;
            acc1[3][0] += a3 * q.x; acc1[3][1] += a3 * q.y; acc1[3][2] += a3 * q.z; acc1[3][3] += a3 * q.w;
        }
        __syncthreads();
    }

    #pragma unroll
    for (int i = 0; i < 4; ++i) {
        const int row = bm + ty * 4 + i;
        if (row >= M) continue;
        #pragma unroll
        for (int j = 0; j < 4; ++j) {
            const int col = bn + tx * 4 + j;
            if (col < dout) {
                C0[(size_t)row * dout + col] = acc0[i][j] + b0[col];
                C1[(size_t)row * dout + col] = acc1[i][j] + b1[col];
            }
        }
    }
}

// ---------------- gathers over fp16 h1, fp16 output ----------------
// dout=192: 2 rows/wave-round (32 lanes x 12B), 4 rounds in flight -> 8 rows/iter.
__global__ __launch_bounds__(256) void gather_d192_h(
    const float* __restrict__ h0, const __half2* __restrict__ h1,
    const int* __restrict__ rowptr, const int* __restrict__ adj,
    const float* __restrict__ dinv, _Float16* __restrict__ out)
{
    const int v = blockIdx.x * 4 + (threadIdx.x >> 6);
    if (v >= NV) return;
    const int lane = threadIdx.x & 63;
    const int sub = lane >> 5;
    const int cu = (lane & 31) * 3;        // half2 column
    const int s = rowptr[v], e = rowptr[v + 1];

    float2 a0 = {0.f, 0.f}, a1 = {0.f, 0.f}, a2 = {0.f, 0.f};

    int j = s;
    const int jend = s + ((e - s) & ~7);
    for (; j < jend; j += 8) {
        const int u0 = adj[j + 0 + sub];
        const int u1 = adj[j + 2 + sub];
        const int u2 = adj[j + 4 + sub];
        const int u3 = adj[j + 6 + sub];
        const __half2* r0 = h1 + (size_t)u0 * 96 + cu;
        const __half2* r1 = h1 + (size_t)u1 * 96 + cu;
        const __half2* r2 = h1 + (size_t)u2 * 96 + cu;
        const __half2* r3 = h1 + (size_t)u3 * 96 + cu;
        const __half2 x00 = r0[0], x01 = r0[1], x02 = r0[2];
        const __half2 x10 = r1[0], x11 = r1[1], x12 = r1[2];
        const __half2 x20 = r2[0], x21 = r2[1], x22 = r2[2];
        const __half2 x30 = r3[0], x31 = r3[1], x32 = r3[2];
        float2 p;
        p = __half22float2(x00); a0.x += p.x; a0.y += p.y;
        p = __half22float2(x01); a1.x += p.x; a1.y += p.y;
        p = __half22float2(x02); a2.x += p.x; a2.y += p.y;
        p = __half22float2(x10); a0.x += p.x; a0.y += p.y;
        p = __half22float2(x11); a1.x += p.x; a1.y += p.y;
        p = __half22float2(x12); a2.x += p.x; a2.y += p.y;
        p = __half22float2(x20); a0.x += p.x; a0.y += p.y;
        p = __half22float2(x21); a1.x += p.x; a1.y += p.y;
        p = __half22float2(x22); a2.x += p.x; a2.y += p.y;
        p = __half22float2(x30); a0.x += p.x; a0.y += p.y;
        p = __half22float2(x31); a1.x += p.x; a1.y += p.y;
        p = __half22float2(x32); a2.x += p.x; a2.y += p.y;
    }
    for (; j < e; j += 2) {
        const int jj = j + sub;
        if (jj < e) {
            const __half2* r = h1 + (size_t)adj[jj] * 96 + cu;
            float2 p;
            p = __half22float2(r[0]); a0.x += p.x; a0.y += p.y;
            p = __half22float2(r[1]); a1.x += p.x; a1.y += p.y;
            p = __half22float2(r[2]); a2.x += p.x; a2.y += p.y;
        }
    }

    a0.x += __shfl_xor(a0.x, 32); a0.y += __shfl_xor(a0.y, 32);
    a1.x += __shfl_xor(a1.x, 32); a1.y += __shfl_xor(a1.y, 32);
    a2.x += __shfl_xor(a2.x, 32); a2.y += __shfl_xor(a2.y, 32);

    if (sub == 0) {
        const float di = dinv[v];
        const size_t base = (size_t)v * 192 + (size_t)cu * 2;
        f16x2 o0, o1, o2;
        o0[0] = (_Float16)fmaxf((h0[base + 0] + a0.x) * di, 0.f);
        o0[1] = (_Float16)fmaxf((h0[base + 1] + a0.y) * di, 0.f);
        o1[0] = (_Float16)fmaxf((h0[base + 2] + a1.x) * di, 0.f);
        o1[1] = (_Float16)fmaxf((h0[base + 3] + a1.y) * di, 0.f);
        o2[0] = (_Float16)fmaxf((h0[base + 4] + a2.x) * di, 0.f);
        o2[1] = (_Float16)fmaxf((h0[base + 5] + a2.y) * di, 0.f);
        *reinterpret_cast<f16x2*>(out + base + 0) = o0;
        *reinterpret_cast<f16x2*>(out + base + 2) = o1;
        *reinterpret_cast<f16x2*>(out + base + 4) = o2;
    }
}

// dout=128: 4 rows/round (16 lanes x 16B), 4 rounds in flight -> 16 rows/iter.
__global__ __launch_bounds__(256) void gather_d128_h(
    const float* __restrict__ h0, const __half2* __restrict__ h1,
    const int* __restrict__ rowptr, const int* __restrict__ adj,
    const float* __restrict__ dinv, _Float16* __restrict__ out)
{
    const int v = blockIdx.x * 4 + (threadIdx.x >> 6);
    if (v >= NV) return;
    const int lane = threadIdx.x & 63;
    const int sub = lane >> 4;             // 0..3
    const int cu = (lane & 15) * 4;        // half2 column
    const int s = rowptr[v], e = rowptr[v + 1];

    float acc[8] = {};

    int j = s;
    const int jend = s + ((e - s) & ~15);
    for (; j < jend; j += 16) {
        const int u0 = adj[j + 0 + sub];
        const int u1 = adj[j + 4 + sub];
        const int u2 = adj[j + 8 + sub];
        const int u3 = adj[j + 12 + sub];
        const int4 w0 = *reinterpret_cast<const int4*>(h1 + (size_t)u0 * 64 + cu);
        const int4 w1 = *reinterpret_cast<const int4*>(h1 + (size_t)u1 * 64 + cu);
        const int4 w2 = *reinterpret_cast<const int4*>(h1 + (size_t)u2 * 64 + cu);
        const int4 w3 = *reinterpret_cast<const int4*>(h1 + (size_t)u3 * 64 + cu);
        #pragma unroll
        for (int t = 0; t < 4; ++t) {
            const float2 p0 = __half22float2(*(const __half2*)(&(&w0.x)[t]));
            const float2 p1 = __half22float2(*(const __half2*)(&(&w1.x)[t]));
            const float2 p2 = __half22float2(*(const __half2*)(&(&w2.x)[t]));
            const float2 p3 = __half22float2(*(const __half2*)(&(&w3.x)[t]));
            acc[2 * t + 0] += (p0.x + p1.x) + (p2.x + p3.x);
            acc[2 * t + 1] += (p0.y + p1.y) + (p2.y + p3.y);
        }
    }
    for (; j < e; j += 4) {
        const int jj = j + sub;
        if (jj < e) {
            const int4 w0 = *reinterpret_cast<const int4*>(h1 + (size_t)adj[jj] * 64 + cu);
            #pragma unroll
            for (int t = 0; t < 4; ++t) {
                const float2 p = __half22float2(*(const __half2*)(&(&w0.x)[t]));
                acc[2 * t + 0] += p.x;
                acc[2 * t + 1] += p.y;
            }
        }
    }

    #pragma unroll
    for (int t = 0; t < 8; ++t) {
        acc[t] += __shfl_xor(acc[t], 16);
        acc[t] += __shfl_xor(acc[t], 32);
    }

    if (sub == 0) {
        const float di = dinv[v];
        const size_t base = (size_t)v * 128 + (size_t)cu * 2;
        f16x8 o;
        #pragma unroll
        for (int t = 0; t < 8; ++t)
            o[t] = (_Float16)fmaxf((h0[base + t] + acc[t]) * di, 0.f);
        *reinterpret_cast<f16x8*>(out + base) = o;
    }
}

// dout=64: 4 rows/round (16 lanes x 8B), 4 rounds in flight -> 16 rows/iter.
__global__ __launch_bounds__(256) void gather_d64_h(
    const float* __restrict__ h0, const __half2* __restrict__ h1,
    const int* __restrict__ rowptr, const int* __restrict__ adj,
    const float* __restrict__ dinv, _Float16* __restrict__ out)
{
    const int v = blockIdx.x * 4 + (threadIdx.x >> 6);
    if (v >= NV) return;
    const int lane = threadIdx.x & 63;
    const int sub = lane >> 4;             // 0..3
    const int cu = (lane & 15) * 2;        // half2 column (2 half2 = 4 halfs per lane)
    const int s = rowptr[v], e = rowptr[v + 1];

    float acc[4] = {};

    int j = s;
    const int jend = s + ((e - s) & ~15);
    for (; j < jend; j += 16) {
        const int u0 = adj[j + 0 + sub];
        const int u1 = adj[j + 4 + sub];
        const int u2 = adj[j + 8 + sub];
        const int u3 = adj[j + 12 + sub];
        const int2 w0 = *reinterpret_cast<const int2*>(h1 + (size_t)u0 * 32 + cu);
        const int2 w1 = *reinterpret_cast<const int2*>(h1 + (size_t)u1 * 32 + cu);
        const int2 w2 = *reinterpret_cast<const int2*>(h1 + (size_t)u2 * 32 + cu);
        const int2 w3 = *reinterpret_cast<const int2*>(h1 + (size_t)u3 * 32 + cu);
        #pragma unroll
        for (int t = 0; t < 2; ++t) {
            const float2 p0 = __half22float2(*(const __half2*)(&(&w0.x)[t]));
            const float2 p1 = __half22float2(*(const __half2*)(&(&w1.x)[t]));
            const float2 p2 = __half22float2(*(const __half2*)(&(&w2.x)[t]));
            const float2 p3 = __half22float2(*(const __half2*)(&(&w3.x)[t]));
            acc[2 * t + 0] += (p0.x + p1.x) + (p2.x + p3.x);
            acc[2 * t + 1] += (p0.y + p1.y) + (p2.y + p3.y);
        }
    }
    for (; j < e; j += 4) {
        const int jj = j + sub;
        if (jj < e) {
            const int2 w0 = *reinterpret_cast<const int2*>(h1 + (size_t)adj[jj] * 32 + cu);
            #pragma unroll
            for (int t = 0; t < 2; ++t) {
                const float2 p = __half22float2(*(const __half2*)(&(&w0.x)[t]));
                acc[2 * t + 0] += p.x;
                acc[2 * t + 1] += p.y;
            }
        }
    }

    #pragma unroll
    for (int t = 0; t < 4; ++t) {
        acc[t] += __shfl_xor(acc[t], 16);
        acc[t] += __shfl_xor(acc[t], 32);
    }

    if (sub == 0) {
        const float di = dinv[v];
        const size_t base = (size_t)v * 64 + (size_t)cu * 2;
        f16x4 o;
        #pragma unroll
        for (int t = 0; t < 4; ++t)
            o[t] = (_Float16)fmaxf((h0[base + t] + acc[t]) * di, 0.f);
        *reinterpret_cast<f16x4*>(out + base) = o;
    }
}

// dout=3 (last layer, fp32 h1, no relu, fp32 out): lane-per-neighbor, butterfly reduce
__global__ __launch_bounds__(256) void gather_d3(
    const float* __restrict__ h0, const float* __restrict__ h1,
    const int* __restrict__ rowptr, const int* __restrict__ adj,
    const float* __restrict__ dinv, float* __restrict__ out)
{
    const int v = blockIdx.x * 4 + (threadIdx.x >> 6);
    if (v >= NV) return;
    const int lane = threadIdx.x & 63;
    const int s = rowptr[v], e = rowptr[v + 1];
    float a0 = 0.f, a1 = 0.f, a2 = 0.f;
    for (int j = s + lane; j < e; j += 64) {
        const float3 r = *reinterpret_cast<const float3*>(h1 + (size_t)adj[j] * 3);
        a0 += r.x; a1 += r.y; a2 += r.z;
    }
    #pragma unroll
    for (int off = 1; off < 64; off <<= 1) {
        a0 += __shfl_xor(a0, off);
        a1 += __shfl_xor(a1, off);
        a2 += __shfl_xor(a2, off);
    }
    if (lane == 0) {
        const float di = dinv[v];
        const size_t base = (size_t)v * 3;
        out[base + 0] = (h0[base + 0] + a0) * di;
        out[base + 1] = (h0[base + 1] + a1) * di;
        out[base + 2] = (h0[base + 2] + a2) * di;
    }
}

extern "C" void kernel_launch(void* const* d_in, const int* in_sizes, int n_in,
                              void* d_out, int out_size, void* d_ws, size_t ws_size,
                              hipStream_t stream) {
    const float* features = (const float*)d_in[0];
    const int*   edges    = (const int*)d_in[1];

    char* ws = (char*)d_ws;
    size_t off = 0;
    auto alloc = [&](size_t bytes) {
        void* p = ws + off;
        off = (off + bytes + 255) & ~(size_t)255;
        return p;
    };
    int*      deg    = (int*)alloc((size_t)NV * sizeof(int));
    float*    dinv   = (float*)alloc((size_t)NV * sizeof(float));
    int*      rowptr = (int*)alloc((size_t)(NV + 1) * sizeof(int));
    int*      fill   = (int*)alloc((size_t)NV * sizeof(int));
    int*      bsum   = (int*)alloc(256 * sizeof(int));
    int*      adj    = (int*)alloc((size_t)2 * NE * sizeof(int));
    float*    bufC0  = (float*)alloc((size_t)NV * 192 * sizeof(float));      // h0 per layer
    void*     bufC1  = alloc((size_t)NV * 192 * sizeof(float));              // h1 (fp16 / fp32 L3)
    _Float16* bufX1  = (_Float16*)alloc((size_t)NV * 192 * sizeof(_Float16)); // x after L0 (also x after L2: d=64 aliases fine size-wise)
    _Float16* bufX2  = (_Float16*)alloc((size_t)NV * 128 * sizeof(_Float16)); // x after L1

    // ---- CSR build ----
    hipMemsetAsync(deg, 0, (size_t)NV * sizeof(int), stream);
    degree_count<<<(2 * NE + 255) / 256, 256, 0, stream>>>(edges, deg, 2 * NE);
    scan_block<<<NBLK, SCAN_B, 0, stream>>>(deg, rowptr, bsum, NV);
    scan_top<<<1, 128, 0, stream>>>(bsum, NBLK);
    finalize_rowptr<<<NBLK, SCAN_B, 0, stream>>>(rowptr, bsum, deg, fill, dinv, NV);
    fill_adj<<<(NE + 255) / 256, 256, 0, stream>>>(edges, fill, adj, NE);

    const int gatherGrid = (NV + 3) / 4;
    const int dims[5] = {256, 192, 128, 64, 3};
    // X pointers per layer (L0 fp32 features; L1+ fp16)
    _Float16* Xh[4] = { nullptr, bufX1, bufX2, bufX1 };  // L3 X aliases bufX1 (free after L1 GEMM)
    _Float16* Xout[3] = { bufX1, bufX2, bufX1 };

    for (int li = 0; li < 4; ++li) {
        const int din  = dims[li];
        const int dout = dims[li + 1];
        const float* W0 = (const float*)d_in[2 + li * 4 + 0];
        const float* b0 = (const float*)d_in[2 + li * 4 + 1];
        const float* W1 = (const float*)d_in[2 + li * 4 + 2];
        const float* b1 = (const float*)d_in[2 + li * 4 + 3];

        if (li == 0) {
            dim3 grid((NV + TBM - 1) / TBM, dout / TBN);
            gemm_dual_mfma<float><<<grid, 256, 0, stream>>>(features, W0, b0, W1, b1,
                                                            bufC0, (_Float16*)bufC1, NV, din, dout);
        } else if (li < 3) {
            dim3 grid((NV + TBM - 1) / TBM, dout / TBN);
            gemm_dual_mfma<_Float16><<<grid, 256, 0, stream>>>(Xh[li], W0, b0, W1, b1,
                                                               bufC0, (_Float16*)bufC1, NV, din, dout);
        } else {
            dim3 grid((NV + BM - 1) / BM, (dout + BN - 1) / BN);
            gemm_dual_bias_f32<<<grid, 256, 0, stream>>>(Xh[li], W0, b0, W1, b1,
                                                         bufC0, (float*)bufC1, NV, din, dout);
        }

        if (li == 0)
            gather_d192_h<<<gatherGrid, 256, 0, stream>>>(bufC0, (const __half2*)bufC1,
                                                          rowptr, adj, dinv, Xout[0]);
        else if (li == 1)
            gather_d128_h<<<gatherGrid, 256, 0, stream>>>(bufC0, (const __half2*)bufC1,
                                                          rowptr, adj, dinv, Xout[1]);
        else if (li == 2)
            gather_d64_h<<<gatherGrid, 256, 0, stream>>>(bufC0, (const __half2*)bufC1,
                                                         rowptr, adj, dinv, Xout[2]);
        else
            gather_d3<<<gatherGrid, 256, 0, stream>>>(bufC0, (const float*)bufC1,
                                                      rowptr, adj, dinv, (float*)d_out);
    }
}

// Round 7
// 761.324 us; speedup vs baseline: 6.3017x; 1.0326x over previous
//
#include <hip/hip_runtime.h>
#include <hip/hip_fp16.h>

#define NV 100000
#define NE 1600000

#define BM 64
#define BN 64
#define BK 16

#define SCAN_B 1024
#define NBLK ((NV + SCAN_B - 1) / SCAN_B)   // 98

typedef __attribute__((ext_vector_type(8))) _Float16 f16x8;
typedef __attribute__((ext_vector_type(4))) _Float16 f16x4;
typedef __attribute__((ext_vector_type(2))) _Float16 f16x2;
typedef __attribute__((ext_vector_type(4))) float f32x4;

// ---------------- degree histogram ----------------
__global__ void degree_count(const int* __restrict__ ef, int* __restrict__ deg, int n) {
    int i = blockIdx.x * blockDim.x + threadIdx.x;
    if (i < n) atomicAdd(&deg[ef[i]], 1);
}

// ---------------- block-level exclusive scan ----------------
__global__ __launch_bounds__(SCAN_B) void scan_block(const int* __restrict__ deg,
                                                     int* __restrict__ part,
                                                     int* __restrict__ bsum, int n) {
    __shared__ int tmp[SCAN_B];
    const int tid = threadIdx.x;
    const int gid = blockIdx.x * SCAN_B + tid;
    int v = (gid < n) ? deg[gid] : 0;
    tmp[tid] = v;
    __syncthreads();
    for (int off = 1; off < SCAN_B; off <<= 1) {
        int t = (tid >= off) ? tmp[tid - off] : 0;
        __syncthreads();
        tmp[tid] += t;
        __syncthreads();
    }
    if (gid < n) part[gid] = tmp[tid] - v;       // exclusive
    if (tid == SCAN_B - 1) bsum[blockIdx.x] = tmp[tid];
}

__global__ __launch_bounds__(128) void scan_top(int* __restrict__ bsum, int nb) {
    __shared__ int tmp[128];
    const int tid = threadIdx.x;
    int v = (tid < nb) ? bsum[tid] : 0;
    tmp[tid] = v;
    __syncthreads();
    for (int off = 1; off < 128; off <<= 1) {
        int t = (tid >= off) ? tmp[tid - off] : 0;
        __syncthreads();
        tmp[tid] += t;
        __syncthreads();
    }
    if (tid < nb) bsum[tid] = tmp[tid] - v;      // exclusive
}

__global__ __launch_bounds__(SCAN_B) void finalize_rowptr(int* __restrict__ rowptr,
                                                          const int* __restrict__ bsum,
                                                          const int* __restrict__ deg,
                                                          int* __restrict__ fill,
                                                          float* __restrict__ dinv, int n) {
    const int gid = blockIdx.x * SCAN_B + threadIdx.x;
    if (gid < n) {
        int r = rowptr[gid] + bsum[blockIdx.x];
        rowptr[gid] = r;
        fill[gid] = r;
        dinv[gid] = 1.0f / (float)deg[gid];
    }
    if (gid == 0) rowptr[n] = 2 * NE;
}

__global__ void fill_adj(const int* __restrict__ edges, int* __restrict__ fill,
                         int* __restrict__ adj, int nE) {
    int e = blockIdx.x * blockDim.x + threadIdx.x;
    if (e >= nE) return;
    const int a = edges[2 * e];
    const int b = edges[2 * e + 1];
    int pa = atomicAdd(&fill[a], 1); adj[pa] = b;
    int pb = atomicAdd(&fill[b], 1); adj[pb] = a;
}

// ---------------- MFMA dual panel-GEMM ----------------
// One block: 96 rows x full dout. Whole A panel (96 x DIN fp16) staged in LDS once;
// loop over NT n-tiles of 64 cols, K in 32-steps. 4 waves (2x2): wave tile 48x32,
// 3x2 fragments of 16x16x32 per output. C0, C1 both fp16.
// A row stride DIN+12 halfs -> bank step 6 (16 distinct banks / quarter-wave, 2-way free).
// B row stride 44 halfs -> bank step 22 (16 distinct banks, 2-way free).
template <typename XT, int DIN, int NT>
__global__ __launch_bounds__(256) void gemm_dual_panel(
    const XT* __restrict__ X,
    const float* __restrict__ W0, const float* __restrict__ b0,
    const float* __restrict__ W1, const float* __restrict__ b1,
    _Float16* __restrict__ C0, _Float16* __restrict__ C1, int M)
{
    constexpr int DOUT = NT * 64;
    constexpr int AST = DIN + 12;        // halfs
    constexpr int BST = 44;              // halfs (32 k + 12 pad)

    __shared__ _Float16 As[96 * AST];
    __shared__ _Float16 Bs[2][64 * BST];

    const int tid = threadIdx.x;
    const int bm = blockIdx.x * 96;
    const int lane = tid & 63;
    const int wid = tid >> 6;
    const int wm = wid >> 1;       // 0..1
    const int wn = wid & 1;        // 0..1
    const int lr = lane & 15;
    const int lk = lane >> 4;

    // ---- stage full A panel ----
    if constexpr (sizeof(XT) == 4) {
        constexpr int QPR = DIN / 4;                 // float4 per row
        for (int idx = tid; idx < 96 * QPR; idx += 256) {
            const int row = idx / QPR, q = idx % QPR;
            const int grow = bm + row;
            float4 v = {0.f, 0.f, 0.f, 0.f};
            if (grow < M)
                v = *reinterpret_cast<const float4*>(&X[(size_t)grow * DIN + q * 4]);
            f16x4 h = { (_Float16)v.x, (_Float16)v.y, (_Float16)v.z, (_Float16)v.w };
            *reinterpret_cast<f16x4*>(&As[row * AST + q * 4]) = h;
        }
    } else {
        constexpr int QPR = DIN / 8;                 // f16x8 per row
        for (int idx = tid; idx < 96 * QPR; idx += 256) {
            const int row = idx / QPR, q = idx % QPR;
            const int grow = bm + row;
            f16x8 h = {};
            if (grow < M)
                h = *reinterpret_cast<const f16x8*>(&X[(size_t)grow * DIN + q * 8]);
            *reinterpret_cast<f16x8*>(&As[row * AST + q * 8]) = h;
        }
    }
    __syncthreads();

    const int ccol = tid & 63;            // B staging: column
    const int kb = (tid >> 6) * 8;        // B staging: k base

    #pragma unroll
    for (int nt = 0; nt < NT; ++nt) {
        const int bn = nt * 64;
        f32x4 acc[2][3][2] = {};

        for (int k0 = 0; k0 < DIN; k0 += 32) {
            // ---- stage B0/B1 transposed: Bs[o][n][k] ----
            {
                const float* pw0 = &W0[(size_t)(k0 + kb) * DOUT + bn + ccol];
                const float* pw1 = &W1[(size_t)(k0 + kb) * DOUT + bn + ccol];
                _Float16* d0 = &Bs[0][ccol * BST + kb];
                _Float16* d1 = &Bs[1][ccol * BST + kb];
                #pragma unroll
                for (int i = 0; i < 8; ++i) {
                    d0[i] = (_Float16)pw0[(size_t)i * DOUT];
                    d1[i] = (_Float16)pw1[(size_t)i * DOUT];
                }
            }
            __syncthreads();

            // ---- fragments + MFMA ----
            f16x8 a[3], b[2][2];
            #pragma unroll
            for (int mf = 0; mf < 3; ++mf)
                a[mf] = *reinterpret_cast<const f16x8*>(
                    &As[(wm * 48 + mf * 16 + lr) * AST + k0 + lk * 8]);
            #pragma unroll
            for (int o = 0; o < 2; ++o)
                #pragma unroll
                for (int nf = 0; nf < 2; ++nf)
                    b[o][nf] = *reinterpret_cast<const f16x8*>(
                        &Bs[o][(wn * 32 + nf * 16 + lr) * BST + lk * 8]);

            #pragma unroll
            for (int o = 0; o < 2; ++o)
                #pragma unroll
                for (int mf = 0; mf < 3; ++mf)
                    #pragma unroll
                    for (int nf = 0; nf < 2; ++nf)
                        acc[o][mf][nf] = __builtin_amdgcn_mfma_f32_16x16x32_f16(
                            a[mf], b[o][nf], acc[o][mf][nf], 0, 0, 0);

            __syncthreads();
        }

        // ---- epilogue: C/D layout col=lane&15, row=(lane>>4)*4+reg ----
        #pragma unroll
        for (int mf = 0; mf < 3; ++mf) {
            #pragma unroll
            for (int reg = 0; reg < 4; ++reg) {
                const int row = bm + wm * 48 + mf * 16 + lk * 4 + reg;
                if (row >= M) continue;
                #pragma unroll
                for (int nf = 0; nf < 2; ++nf) {
                    const int c = bn + wn * 32 + nf * 16 + lr;
                    C0[(size_t)row * DOUT + c] = (_Float16)(acc[0][mf][nf][reg] + b0[c]);
                    C1[(size_t)row * DOUT + c] = (_Float16)(acc[1][mf][nf][reg] + b1[c]);
                }
            }
        }
    }
}

// ---------------- vector dual GEMM (layer 3 only: dout=3, fp16 X, fp32 out) ----------------
__global__ __launch_bounds__(256) void gemm_dual_bias_f32(
    const _Float16* __restrict__ X,
    const float* __restrict__ W0, const float* __restrict__ b0,
    const float* __restrict__ W1, const float* __restrict__ b1,
    float* __restrict__ C0, float* __restrict__ C1,
    int M, int din, int dout)
{
    __shared__ float As[BM][BK + 1];
    __shared__ float Bs0[BK][BN];
    __shared__ float Bs1[BK][BN];

    const int tid = threadIdx.x;
    const int bm = blockIdx.x * BM;
    const int bn = blockIdx.y * BN;
    const int tx = tid & 15;
    const int ty = tid >> 4;

    const int ar = tid >> 2;
    const int ac = (tid & 3) * 4;
    const int br = tid >> 4;
    const int bc = (tid & 15) * 4;

    float acc0[4][4] = {};
    float acc1[4][4] = {};

    for (int k0 = 0; k0 < din; k0 += BK) {
        {
            const int grow = bm + ar;
            if (grow < M) {
                const f16x4 v = *reinterpret_cast<const f16x4*>(&X[(size_t)grow * din + k0 + ac]);
                As[ar][ac + 0] = (float)v[0]; As[ar][ac + 1] = (float)v[1];
                As[ar][ac + 2] = (float)v[2]; As[ar][ac + 3] = (float)v[3];
            } else {
                As[ar][ac + 0] = 0.f; As[ar][ac + 1] = 0.f;
                As[ar][ac + 2] = 0.f; As[ar][ac + 3] = 0.f;
            }
        }
        {
            const int gk = k0 + br;
            const int gc = bn + bc;
            float4 v0, v1;
            v0.x = (gc + 0 < dout) ? W0[(size_t)gk * dout + gc + 0] : 0.f;
            v0.y = (gc + 1 < dout) ? W0[(size_t)gk * dout + gc + 1] : 0.f;
            v0.z = (gc + 2 < dout) ? W0[(size_t)gk * dout + gc + 2] : 0.f;
            v0.w = (gc + 3 < dout) ? W0[(size_t)gk * dout + gc + 3] : 0.f;
            v1.x = (gc + 0 < dout) ? W1[(size_t)gk * dout + gc + 0] : 0.f;
            v1.y = (gc + 1 < dout) ? W1[(size_t)gk * dout + gc + 1] : 0.f;
            v1.z = (gc + 2 < dout) ? W1[(size_t)gk * dout + gc + 2] : 0.f;
            v1.w = (gc + 3 < dout) ? W1[(size_t)gk * dout + gc + 3] : 0.f;
            *reinterpret_cast<float4*>(&Bs0[br][bc]) = v0;
            *reinterpret_cast<float4*>(&Bs1[br][bc]) = v1;
        }
        __syncthreads();

        #pragma unroll
        for (int kk = 0; kk < BK; ++kk) {
            const float a0 = As[ty * 4 + 0][kk];
            const float a1 = As[ty * 4 + 1][kk];
            const float a2 = As[ty * 4 + 2][kk];
            const float a3 = As[ty * 4 + 3][kk];
            const float4 p = *reinterpret_cast<const float4*>(&Bs0[kk][tx * 4]);
            const float4 q = *reinterpret_cast<const float4*>(&Bs1[kk][tx * 4]);
            acc0[0][0] += a0 * p.x; acc0[0][1] += a0 * p.y; acc0[0][2] += a0 * p.z; acc0[0][3] += a0 * p.w;
            acc0[1][0] += a1 * p.x; acc0[1][1] += a1 * p.y; acc0[1][2] += a1 * p.z; acc0[1][3] += a1 * p.w;
            acc0[2][0] += a2 * p.x; acc0[2][1] += a2 * p.y; acc0[2][2] += a2 * p.z; acc0[2][3] += a2 * p.w;
            acc0[3][0] += a3 * p.x; acc0[3][1] += a3 * p.y; acc0[3][2] += a3 * p.z; acc0[3][3] += a3 * p.w;
            acc1[0][0] += a0 * q.x; acc1[0][1] += a0 * q.y; acc1[0][2] += a0 * q.z; acc1[0][3] += a0 * q.w;
            acc1[1][0] += a1 * q.x; acc1[1][1] += a1 * q.y; acc1[1][2] += a1 * q.z; acc1[1][3] += a1 * q.w;
            acc1[2][0] += a2 * q.x; acc1[2][1] += a2 * q.y; acc1[2][2] += a2 * q.z; acc1[2][3] += a2 * q.w;
            acc1[3][0] += a3 * q.x; acc1[3][1] += a3 * q.y; acc1[3][2] += a3 * q.z; acc1[3][3] += a3 * q.w;
        }
        __syncthreads();
    }

    #pragma unroll
    for (int i = 0; i < 4; ++i) {
        const int row = bm + ty * 4 + i;
        if (row >= M) continue;
        #pragma unroll
        for (int j = 0; j < 4; ++j) {
            const int col = bn + tx * 4 + j;
            if (col < dout) {
                C0[(size_t)row * dout + col] = acc0[i][j] + b0[col];
                C1[(size_t)row * dout + col] = acc1[i][j] + b1[col];
            }
        }
    }
}

// ---------------- gathers over fp16 h1 + fp16 h0, fp16 output ----------------
// dout=192: 2 rows/round (32 lanes x 12B), 4 rounds in flight.
__global__ __launch_bounds__(256) void gather_d192_h(
    const _Float16* __restrict__ h0, const __half2* __restrict__ h1,
    const int* __restrict__ rowptr, const int* __restrict__ adj,
    const float* __restrict__ dinv, _Float16* __restrict__ out)
{
    const int v = blockIdx.x * 4 + (threadIdx.x >> 6);
    if (v >= NV) return;
    const int lane = threadIdx.x & 63;
    const int sub = lane >> 5;
    const int cu = (lane & 31) * 3;        // half2 column
    const int s = rowptr[v], e = rowptr[v + 1];

    float2 a0 = {0.f, 0.f}, a1 = {0.f, 0.f}, a2 = {0.f, 0.f};

    int j = s;
    const int jend = s + ((e - s) & ~7);
    for (; j < jend; j += 8) {
        const int u0 = adj[j + 0 + sub];
        const int u1 = adj[j + 2 + sub];
        const int u2 = adj[j + 4 + sub];
        const int u3 = adj[j + 6 + sub];
        const __half2* r0 = h1 + (size_t)u0 * 96 + cu;
        const __half2* r1 = h1 + (size_t)u1 * 96 + cu;
        const __half2* r2 = h1 + (size_t)u2 * 96 + cu;
        const __half2* r3 = h1 + (size_t)u3 * 96 + cu;
        const __half2 x00 = r0[0], x01 = r0[1], x02 = r0[2];
        const __half2 x10 = r1[0], x11 = r1[1], x12 = r1[2];
        const __half2 x20 = r2[0], x21 = r2[1], x22 = r2[2];
        const __half2 x30 = r3[0], x31 = r3[1], x32 = r3[2];
        float2 p;
        p = __half22float2(x00); a0.x += p.x; a0.y += p.y;
        p = __half22float2(x01); a1.x += p.x; a1.y += p.y;
        p = __half22float2(x02); a2.x += p.x; a2.y += p.y;
        p = __half22float2(x10); a0.x += p.x; a0.y += p.y;
        p = __half22float2(x11); a1.x += p.x; a1.y += p.y;
        p = __half22float2(x12); a2.x += p.x; a2.y += p.y;
        p = __half22float2(x20); a0.x += p.x; a0.y += p.y;
        p = __half22float2(x21); a1.x += p.x; a1.y += p.y;
        p = __half22float2(x22); a2.x += p.x; a2.y += p.y;
        p = __half22float2(x30); a0.x += p.x; a0.y += p.y;
        p = __half22float2(x31); a1.x += p.x; a1.y += p.y;
        p = __half22float2(x32); a2.x += p.x; a2.y += p.y;
    }
    for (; j < e; j += 2) {
        const int jj = j + sub;
        if (jj < e) {
            const __half2* r = h1 + (size_t)adj[jj] * 96 + cu;
            float2 p;
            p = __half22float2(r[0]); a0.x += p.x; a0.y += p.y;
            p = __half22float2(r[1]); a1.x += p.x; a1.y += p.y;
            p = __half22float2(r[2]); a2.x += p.x; a2.y += p.y;
        }
    }

    a0.x += __shfl_xor(a0.x, 32); a0.y += __shfl_xor(a0.y, 32);
    a1.x += __shfl_xor(a1.x, 32); a1.y += __shfl_xor(a1.y, 32);
    a2.x += __shfl_xor(a2.x, 32); a2.y += __shfl_xor(a2.y, 32);

    if (sub == 0) {
        const float di = dinv[v];
        const size_t base = (size_t)v * 192 + (size_t)cu * 2;
        const f16x2 z0 = *reinterpret_cast<const f16x2*>(h0 + base + 0);
        const f16x2 z1 = *reinterpret_cast<const f16x2*>(h0 + base + 2);
        const f16x2 z2 = *reinterpret_cast<const f16x2*>(h0 + base + 4);
        f16x2 o0, o1, o2;
        o0[0] = (_Float16)fmaxf(((float)z0[0] + a0.x) * di, 0.f);
        o0[1] = (_Float16)fmaxf(((float)z0[1] + a0.y) * di, 0.f);
        o1[0] = (_Float16)fmaxf(((float)z1[0] + a1.x) * di, 0.f);
        o1[1] = (_Float16)fmaxf(((float)z1[1] + a1.y) * di, 0.f);
        o2[0] = (_Float16)fmaxf(((float)z2[0] + a2.x) * di, 0.f);
        o2[1] = (_Float16)fmaxf(((float)z2[1] + a2.y) * di, 0.f);
        *reinterpret_cast<f16x2*>(out + base + 0) = o0;
        *reinterpret_cast<f16x2*>(out + base + 2) = o1;
        *reinterpret_cast<f16x2*>(out + base + 4) = o2;
    }
}

// dout=128: 4 rows/round (16 lanes x 16B), 4 rounds in flight.
__global__ __launch_bounds__(256) void gather_d128_h(
    const _Float16* __restrict__ h0, const __half2* __restrict__ h1,
    const int* __restrict__ rowptr, const int* __restrict__ adj,
    const float* __restrict__ dinv, _Float16* __restrict__ out)
{
    const int v = blockIdx.x * 4 + (threadIdx.x >> 6);
    if (v >= NV) return;
    const int lane = threadIdx.x & 63;
    const int sub = lane >> 4;             // 0..3
    const int cu = (lane & 15) * 4;        // half2 column
    const int s = rowptr[v], e = rowptr[v + 1];

    float acc[8] = {};

    int j = s;
    const int jend = s + ((e - s) & ~15);
    for (; j < jend; j += 16) {
        const int u0 = adj[j + 0 + sub];
        const int u1 = adj[j + 4 + sub];
        const int u2 = adj[j + 8 + sub];
        const int u3 = adj[j + 12 + sub];
        const int4 w0 = *reinterpret_cast<const int4*>(h1 + (size_t)u0 * 64 + cu);
        const int4 w1 = *reinterpret_cast<const int4*>(h1 + (size_t)u1 * 64 + cu);
        const int4 w2 = *reinterpret_cast<const int4*>(h1 + (size_t)u2 * 64 + cu);
        const int4 w3 = *reinterpret_cast<const int4*>(h1 + (size_t)u3 * 64 + cu);
        #pragma unroll
        for (int t = 0; t < 4; ++t) {
            const float2 p0 = __half22float2(*(const __half2*)(&(&w0.x)[t]));
            const float2 p1 = __half22float2(*(const __half2*)(&(&w1.x)[t]));
            const float2 p2 = __half22float2(*(const __half2*)(&(&w2.x)[t]));
            const float2 p3 = __half22float2(*(const __half2*)(&(&w3.x)[t]));
            acc[2 * t + 0] += (p0.x + p1.x) + (p2.x + p3.x);
            acc[2 * t + 1] += (p0.y + p1.y) + (p2.y + p3.y);
        }
    }
    for (; j < e; j += 4) {
        const int jj = j + sub;
        if (jj < e) {
            const int4 w0 = *reinterpret_cast<const int4*>(h1 + (size_t)adj[jj] * 64 + cu);
            #pragma unroll
            for (int t = 0; t < 4; ++t) {
                const float2 p = __half22float2(*(const __half2*)(&(&w0.x)[t]));
                acc[2 * t + 0] += p.x;
                acc[2 * t + 1] += p.y;
            }
        }
    }

    #pragma unroll
    for (int t = 0; t < 8; ++t) {
        acc[t] += __shfl_xor(acc[t], 16);
        acc[t] += __shfl_xor(acc[t], 32);
    }

    if (sub == 0) {
        const float di = dinv[v];
        const size_t base = (size_t)v * 128 + (size_t)cu * 2;
        const f16x8 z = *reinterpret_cast<const f16x8*>(h0 + base);
        f16x8 o;
        #pragma unroll
        for (int t = 0; t < 8; ++t)
            o[t] = (_Float16)fmaxf(((float)z[t] + acc[t]) * di, 0.f);
        *reinterpret_cast<f16x8*>(out + base) = o;
    }
}

// dout=64: 4 rows/round (16 lanes x 8B), 4 rounds in flight.
__global__ __launch_bounds__(256) void gather_d64_h(
    const _Float16* __restrict__ h0, const __half2* __restrict__ h1,
    const int* __restrict__ rowptr, const int* __restrict__ adj,
    const float* __restrict__ dinv, _Float16* __restrict__ out)
{
    const int v = blockIdx.x * 4 + (threadIdx.x >> 6);
    if (v >= NV) return;
    const int lane = threadIdx.x & 63;
    const int sub = lane >> 4;             // 0..3
    const int cu = (lane & 15) * 2;        // half2 column
    const int s = rowptr[v], e = rowptr[v + 1];

    float acc[4] = {};

    int j = s;
    const int jend = s + ((e - s) & ~15);
    for (; j < jend; j += 16) {
        const int u0 = adj[j + 0 + sub];
        const int u1 = adj[j + 4 + sub];
        const int u2 = adj[j + 8 + sub];
        const int u3 = adj[j + 12 + sub];
        const int2 w0 = *reinterpret_cast<const int2*>(h1 + (size_t)u0 * 32 + cu);
        const int2 w1 = *reinterpret_cast<const int2*>(h1 + (size_t)u1 * 32 + cu);
        const int2 w2 = *reinterpret_cast<const int2*>(h1 + (size_t)u2 * 32 + cu);
        const int2 w3 = *reinterpret_cast<const int2*>(h1 + (size_t)u3 * 32 + cu);
        #pragma unroll
        for (int t = 0; t < 2; ++t) {
            const float2 p0 = __half22float2(*(const __half2*)(&(&w0.x)[t]));
            const float2 p1 = __half22float2(*(const __half2*)(&(&w1.x)[t]));
            const float2 p2 = __half22float2(*(const __half2*)(&(&w2.x)[t]));
            const float2 p3 = __half22float2(*(const __half2*)(&(&w3.x)[t]));
            acc[2 * t + 0] += (p0.x + p1.x) + (p2.x + p3.x);
            acc[2 * t + 1] += (p0.y + p1.y) + (p2.y + p3.y);
        }
    }
    for (; j < e; j += 4) {
        const int jj = j + sub;
        if (jj < e) {
            const int2 w0 = *reinterpret_cast<const int2*>(h1 + (size_t)adj[jj] * 32 + cu);
            #pragma unroll
            for (int t = 0; t < 2; ++t) {
                const float2 p = __half22float2(*(const __half2*)(&(&w0.x)[t]));
                acc[2 * t + 0] += p.x;
                acc[2 * t + 1] += p.y;
            }
        }
    }

    #pragma unroll
    for (int t = 0; t < 4; ++t) {
        acc[t] += __shfl_xor(acc[t], 16);
        acc[t] += __shfl_xor(acc[t], 32);
    }

    if (sub == 0) {
        const float di = dinv[v];
        const size_t base = (size_t)v * 64 + (size_t)cu * 2;
        const f16x4 z = *reinterpret_cast<const f16x4*>(h0 + base);
        f16x4 o;
        #pragma unroll
        for (int t = 0; t < 4; ++t)
            o[t] = (_Float16)fmaxf(((float)z[t] + acc[t]) * di, 0.f);
        *reinterpret_cast<f16x4*>(out + base) = o;
    }
}

// dout=3 (last layer, fp32 h0/h1, no relu, fp32 out)
__global__ __launch_bounds__(256) void gather_d3(
    const float* __restrict__ h0, const float* __restrict__ h1,
    const int* __restrict__ rowptr, const int* __restrict__ adj,
    const float* __restrict__ dinv, float* __restrict__ out)
{
    const int v = blockIdx.x * 4 + (threadIdx.x >> 6);
    if (v >= NV) return;
    const int lane = threadIdx.x & 63;
    const int s = rowptr[v], e = rowptr[v + 1];
    float a0 = 0.f, a1 = 0.f, a2 = 0.f;
    for (int j = s + lane; j < e; j += 64) {
        const float3 r = *reinterpret_cast<const float3*>(h1 + (size_t)adj[j] * 3);
        a0 += r.x; a1 += r.y; a2 += r.z;
    }
    #pragma unroll
    for (int off = 1; off < 64; off <<= 1) {
        a0 += __shfl_xor(a0, off);
        a1 += __shfl_xor(a1, off);
        a2 += __shfl_xor(a2, off);
    }
    if (lane == 0) {
        const float di = dinv[v];
        const size_t base = (size_t)v * 3;
        out[base + 0] = (h0[base + 0] + a0) * di;
        out[base + 1] = (h0[base + 1] + a1) * di;
        out[base + 2] = (h0[base + 2] + a2) * di;
    }
}

extern "C" void kernel_launch(void* const* d_in, const int* in_sizes, int n_in,
                              void* d_out, int out_size, void* d_ws, size_t ws_size,
                              hipStream_t stream) {
    const float* features = (const float*)d_in[0];
    const int*   edges    = (const int*)d_in[1];

    char* ws = (char*)d_ws;
    size_t off = 0;
    auto alloc = [&](size_t bytes) {
        void* p = ws + off;
        off = (off + bytes + 255) & ~(size_t)255;
        return p;
    };
    int*      deg    = (int*)alloc((size_t)NV * sizeof(int));
    float*    dinv   = (float*)alloc((size_t)NV * sizeof(float));
    int*      rowptr = (int*)alloc((size_t)(NV + 1) * sizeof(int));
    int*      fill   = (int*)alloc((size_t)NV * sizeof(int));
    int*      bsum   = (int*)alloc(256 * sizeof(int));
    int*      adj    = (int*)alloc((size_t)2 * NE * sizeof(int));
    _Float16* hC0    = (_Float16*)alloc((size_t)NV * 192 * sizeof(_Float16)); // h0 (fp16)
    _Float16* hC1    = (_Float16*)alloc((size_t)NV * 192 * sizeof(_Float16)); // h1 (fp16)
    _Float16* bufX1  = (_Float16*)alloc((size_t)NV * 192 * sizeof(_Float16)); // x after L0 / L2
    _Float16* bufX2  = (_Float16*)alloc((size_t)NV * 128 * sizeof(_Float16)); // x after L1
    float*    c0f    = (float*)alloc((size_t)NV * 3 * sizeof(float));         // L3 h0
    float*    c1f    = (float*)alloc((size_t)NV * 3 * sizeof(float));         // L3 h1

    // ---- CSR build ----
    hipMemsetAsync(deg, 0, (size_t)NV * sizeof(int), stream);
    degree_count<<<(2 * NE + 255) / 256, 256, 0, stream>>>(edges, deg, 2 * NE);
    scan_block<<<NBLK, SCAN_B, 0, stream>>>(deg, rowptr, bsum, NV);
    scan_top<<<1, 128, 0, stream>>>(bsum, NBLK);
    finalize_rowptr<<<NBLK, SCAN_B, 0, stream>>>(rowptr, bsum, deg, fill, dinv, NV);
    fill_adj<<<(NE + 255) / 256, 256, 0, stream>>>(edges, fill, adj, NE);

    const int gatherGrid = (NV + 3) / 4;
    const int panelGrid = (NV + 95) / 96;

    // ---- layer 0: 256 -> 192 ----
    gemm_dual_panel<float, 256, 3><<<panelGrid, 256, 0, stream>>>(
        features,
        (const float*)d_in[2], (const float*)d_in[3],
        (const float*)d_in[4], (const float*)d_in[5],
        hC0, hC1, NV);
    gather_d192_h<<<gatherGrid, 256, 0, stream>>>(hC0, (const __half2*)hC1,
                                                  rowptr, adj, dinv, bufX1);

    // ---- layer 1: 192 -> 128 ----
    gemm_dual_panel<_Float16, 192, 2><<<panelGrid, 256, 0, stream>>>(
        bufX1,
        (const float*)d_in[6], (const float*)d_in[7],
        (const float*)d_in[8], (const float*)d_in[9],
        hC0, hC1, NV);
    gather_d128_h<<<gatherGrid, 256, 0, stream>>>(hC0, (const __half2*)hC1,
                                                  rowptr, adj, dinv, bufX2);

    // ---- layer 2: 128 -> 64 ----
    gemm_dual_panel<_Float16, 128, 1><<<panelGrid, 256, 0, stream>>>(
        bufX2,
        (const float*)d_in[10], (const float*)d_in[11],
        (const float*)d_in[12], (const float*)d_in[13],
        hC0, hC1, NV);
    gather_d64_h<<<gatherGrid, 256, 0, stream>>>(hC0, (const __half2*)hC1,
                                                 rowptr, adj, dinv, bufX1);

    // ---- layer 3: 64 -> 3 (fp32 epilogue path) ----
    {
        dim3 grid((NV + BM - 1) / BM, 1);
        gemm_dual_bias_f32<<<grid, 256, 0, stream>>>(
            bufX1,
            (const float*)d_in[14], (const float*)d_in[15],
            (const float*)d_in[16], (const float*)d_in[17],
            c0f, c1f, NV, 64, 3);
        gather_d3<<<gatherGrid, 256, 0, stream>>>(c0f, c1f, rowptr, adj, dinv, (float*)d_out);
    }
}

// Round 8
// 736.175 us; speedup vs baseline: 6.5170x; 1.0342x over previous
//
#include <hip/hip_runtime.h>
#include <hip/hip_fp16.h>

#define NV 100000
#define NE 1600000

#define BM 64
#define BN 64
#define BK 16

#define SCAN_B 1024
#define NBLK ((NV + SCAN_B - 1) / SCAN_B)   // 98

typedef __attribute__((ext_vector_type(8))) _Float16 f16x8;
typedef __attribute__((ext_vector_type(4))) _Float16 f16x4;
typedef __attribute__((ext_vector_type(2))) _Float16 f16x2;
typedef __attribute__((ext_vector_type(4))) float f32x4;

// ---------------- degree histogram ----------------
__global__ void degree_count(const int* __restrict__ ef, int* __restrict__ deg, int n) {
    int i = blockIdx.x * blockDim.x + threadIdx.x;
    if (i < n) atomicAdd(&deg[ef[i]], 1);
}

// ---------------- block-level exclusive scan ----------------
__global__ __launch_bounds__(SCAN_B) void scan_block(const int* __restrict__ deg,
                                                     int* __restrict__ part,
                                                     int* __restrict__ bsum, int n) {
    __shared__ int tmp[SCAN_B];
    const int tid = threadIdx.x;
    const int gid = blockIdx.x * SCAN_B + tid;
    int v = (gid < n) ? deg[gid] : 0;
    tmp[tid] = v;
    __syncthreads();
    for (int off = 1; off < SCAN_B; off <<= 1) {
        int t = (tid >= off) ? tmp[tid - off] : 0;
        __syncthreads();
        tmp[tid] += t;
        __syncthreads();
    }
    if (gid < n) part[gid] = tmp[tid] - v;       // exclusive
    if (tid == SCAN_B - 1) bsum[blockIdx.x] = tmp[tid];
}

__global__ __launch_bounds__(128) void scan_top(int* __restrict__ bsum, int nb) {
    __shared__ int tmp[128];
    const int tid = threadIdx.x;
    int v = (tid < nb) ? bsum[tid] : 0;
    tmp[tid] = v;
    __syncthreads();
    for (int off = 1; off < 128; off <<= 1) {
        int t = (tid >= off) ? tmp[tid - off] : 0;
        __syncthreads();
        tmp[tid] += t;
        __syncthreads();
    }
    if (tid < nb) bsum[tid] = tmp[tid] - v;      // exclusive
}

__global__ __launch_bounds__(SCAN_B) void finalize_rowptr(int* __restrict__ rowptr,
                                                          const int* __restrict__ bsum,
                                                          const int* __restrict__ deg,
                                                          int* __restrict__ fill,
                                                          float* __restrict__ dinv, int n) {
    const int gid = blockIdx.x * SCAN_B + threadIdx.x;
    if (gid < n) {
        int r = rowptr[gid] + bsum[blockIdx.x];
        rowptr[gid] = r;
        fill[gid] = r;
        dinv[gid] = 1.0f / (float)deg[gid];
    }
    if (gid == 0) rowptr[n] = 2 * NE;
}

__global__ void fill_adj(const int* __restrict__ edges, int* __restrict__ fill,
                         int* __restrict__ adj, int nE) {
    int e = blockIdx.x * blockDim.x + threadIdx.x;
    if (e >= nE) return;
    const int a = edges[2 * e];
    const int b = edges[2 * e + 1];
    int pa = atomicAdd(&fill[a], 1); adj[pa] = b;
    int pb = atomicAdd(&fill[b], 1); adj[pb] = a;
}

// ---------------- weight convert+transpose: W[din][dout] fp32 -> WT[dout][din] fp16 ----------------
__global__ void convert_wt(const float* __restrict__ W, _Float16* __restrict__ WT,
                           int din, int dout) {
    int i = blockIdx.x * blockDim.x + threadIdx.x;
    if (i >= din * dout) return;
    const int k = i / dout, n = i % dout;
    WT[(size_t)n * din + k] = (_Float16)W[i];
}

// ---------------- MFMA dual GEMM, A in registers, WT fp16 pre-transposed ----------------
// Block = 64 rows x full DOUT. 4 waves (2x2): wave tile 32x32 per n-tile.
// A fragments for ALL of K live in registers (loaded once). B staged per 64-K chunk.
template <typename XT, int DIN, int NT>
__global__ __launch_bounds__(256) void gemm_dual_reg(
    const XT* __restrict__ X,
    const _Float16* __restrict__ WT0, const float* __restrict__ b0,
    const _Float16* __restrict__ WT1, const float* __restrict__ b1,
    _Float16* __restrict__ C0, _Float16* __restrict__ C1, int M)
{
    constexpr int DOUT = NT * 64;
    constexpr int NKS = DIN / 32;        // 32-K slices
    constexpr int NKC = DIN / 64;        // 64-K chunks
    constexpr int BST = 72;              // halfs per col (64 k + 8 pad; 144B, 16B-aligned)

    __shared__ _Float16 Bs[2][64 * BST];   // 18.4 KB

    const int tid = threadIdx.x;
    const int bm = blockIdx.x * 64;
    const int lane = tid & 63;
    const int wid = tid >> 6;
    const int wm = wid >> 1;       // row half 0..1
    const int wn = wid & 1;        // col half 0..1
    const int lr = lane & 15;
    const int lk = lane >> 4;

    // ---- A fragments -> registers (static indexing; ~4*NKS*2 VGPRs) ----
    f16x8 areg[NKS][2];
    #pragma unroll
    for (int ks = 0; ks < NKS; ++ks) {
        #pragma unroll
        for (int mf = 0; mf < 2; ++mf) {
            const int row = bm + wm * 32 + mf * 16 + lr;
            const int k = ks * 32 + lk * 8;
            f16x8 h = {};
            if (row < M) {
                if constexpr (sizeof(XT) == 4) {
                    const float4 v0 = *reinterpret_cast<const float4*>(&X[(size_t)row * DIN + k]);
                    const float4 v1 = *reinterpret_cast<const float4*>(&X[(size_t)row * DIN + k + 4]);
                    h[0] = (_Float16)v0.x; h[1] = (_Float16)v0.y;
                    h[2] = (_Float16)v0.z; h[3] = (_Float16)v0.w;
                    h[4] = (_Float16)v1.x; h[5] = (_Float16)v1.y;
                    h[6] = (_Float16)v1.z; h[7] = (_Float16)v1.w;
                } else {
                    h = *reinterpret_cast<const f16x8*>(&X[(size_t)row * DIN + k]);
                }
            }
            areg[ks][mf] = h;
        }
    }

    // B staging: thread t copies 16 halfs of col (t>>2) at k-offset (t&3)*16.
    const int scol = tid >> 2;
    const int skb = (tid & 3) * 16;

    for (int nt = 0; nt < NT; ++nt) {
        f32x4 acc[2][2][2] = {};   // [o][mf][nf]

        #pragma unroll
        for (int kc = 0; kc < NKC; ++kc) {
            {
                const size_t srcoff = (size_t)(nt * 64 + scol) * DIN + kc * 64 + skb;
                *reinterpret_cast<f16x8*>(&Bs[0][scol * BST + skb]) =
                    *reinterpret_cast<const f16x8*>(&WT0[srcoff]);
                *reinterpret_cast<f16x8*>(&Bs[0][scol * BST + skb + 8]) =
                    *reinterpret_cast<const f16x8*>(&WT0[srcoff + 8]);
                *reinterpret_cast<f16x8*>(&Bs[1][scol * BST + skb]) =
                    *reinterpret_cast<const f16x8*>(&WT1[srcoff]);
                *reinterpret_cast<f16x8*>(&Bs[1][scol * BST + skb + 8]) =
                    *reinterpret_cast<const f16x8*>(&WT1[srcoff + 8]);
            }
            __syncthreads();

            #pragma unroll
            for (int k2 = 0; k2 < 2; ++k2) {
                const int ks = kc * 2 + k2;
                f16x8 b[2][2];
                #pragma unroll
                for (int o = 0; o < 2; ++o)
                    #pragma unroll
                    for (int nf = 0; nf < 2; ++nf)
                        b[o][nf] = *reinterpret_cast<const f16x8*>(
                            &Bs[o][(wn * 32 + nf * 16 + lr) * BST + k2 * 32 + lk * 8]);
                #pragma unroll
                for (int o = 0; o < 2; ++o)
                    #pragma unroll
                    for (int mf = 0; mf < 2; ++mf)
                        #pragma unroll
                        for (int nf = 0; nf < 2; ++nf)
                            acc[o][mf][nf] = __builtin_amdgcn_mfma_f32_16x16x32_f16(
                                areg[ks][mf], b[o][nf], acc[o][mf][nf], 0, 0, 0);
            }
            __syncthreads();
        }

        // ---- epilogue: C/D layout col=lane&15, row=(lane>>4)*4+reg ----
        #pragma unroll
        for (int mf = 0; mf < 2; ++mf) {
            #pragma unroll
            for (int reg = 0; reg < 4; ++reg) {
                const int row = bm + wm * 32 + mf * 16 + lk * 4 + reg;
                if (row >= M) continue;
                #pragma unroll
                for (int nf = 0; nf < 2; ++nf) {
                    const int c = nt * 64 + wn * 32 + nf * 16 + lr;
                    C0[(size_t)row * DOUT + c] = (_Float16)(acc[0][mf][nf][reg] + b0[c]);
                    C1[(size_t)row * DOUT + c] = (_Float16)(acc[1][mf][nf][reg] + b1[c]);
                }
            }
        }
    }
}

// ---------------- vector dual GEMM (layer 3 only: dout=3, fp16 X, fp32 out) ----------------
__global__ __launch_bounds__(256) void gemm_dual_bias_f32(
    const _Float16* __restrict__ X,
    const float* __restrict__ W0, const float* __restrict__ b0,
    const float* __restrict__ W1, const float* __restrict__ b1,
    float* __restrict__ C0, float* __restrict__ C1,
    int M, int din, int dout)
{
    __shared__ float As[BM][BK + 1];
    __shared__ float Bs0[BK][BN];
    __shared__ float Bs1[BK][BN];

    const int tid = threadIdx.x;
    const int bm = blockIdx.x * BM;
    const int bn = blockIdx.y * BN;
    const int tx = tid & 15;
    const int ty = tid >> 4;

    const int ar = tid >> 2;
    const int ac = (tid & 3) * 4;
    const int br = tid >> 4;
    const int bc = (tid & 15) * 4;

    float acc0[4][4] = {};
    float acc1[4][4] = {};

    for (int k0 = 0; k0 < din; k0 += BK) {
        {
            const int grow = bm + ar;
            if (grow < M) {
                const f16x4 v = *reinterpret_cast<const f16x4*>(&X[(size_t)grow * din + k0 + ac]);
                As[ar][ac + 0] = (float)v[0]; As[ar][ac + 1] = (float)v[1];
                As[ar][ac + 2] = (float)v[2]; As[ar][ac + 3] = (float)v[3];
            } else {
                As[ar][ac + 0] = 0.f; As[ar][ac + 1] = 0.f;
                As[ar][ac + 2] = 0.f; As[ar][ac + 3] = 0.f;
            }
        }
        {
            const int gk = k0 + br;
            const int gc = bn + bc;
            float4 v0, v1;
            v0.x = (gc + 0 < dout) ? W0[(size_t)gk * dout + gc + 0] : 0.f;
            v0.y = (gc + 1 < dout) ? W0[(size_t)gk * dout + gc + 1] : 0.f;
            v0.z = (gc + 2 < dout) ? W0[(size_t)gk * dout + gc + 2] : 0.f;
            v0.w = (gc + 3 < dout) ? W0[(size_t)gk * dout + gc + 3] : 0.f;
            v1.x = (gc + 0 < dout) ? W1[(size_t)gk * dout + gc + 0] : 0.f;
            v1.y = (gc + 1 < dout) ? W1[(size_t)gk * dout + gc + 1] : 0.f;
            v1.z = (gc + 2 < dout) ? W1[(size_t)gk * dout + gc + 2] : 0.f;
            v1.w = (gc + 3 < dout) ? W1[(size_t)gk * dout + gc + 3] : 0.f;
            *reinterpret_cast<float4*>(&Bs0[br][bc]) = v0;
            *reinterpret_cast<float4*>(&Bs1[br][bc]) = v1;
        }
        __syncthreads();

        #pragma unroll
        for (int kk = 0; kk < BK; ++kk) {
            const float a0 = As[ty * 4 + 0][kk];
            const float a1 = As[ty * 4 + 1][kk];
            const float a2 = As[ty * 4 + 2][kk];
            const float a3 = As[ty * 4 + 3][kk];
            const float4 p = *reinterpret_cast<const float4*>(&Bs0[kk][tx * 4]);
            const float4 q = *reinterpret_cast<const float4*>(&Bs1[kk][tx * 4]);
            acc0[0][0] += a0 * p.x; acc0[0][1] += a0 * p.y; acc0[0][2] += a0 * p.z; acc0[0][3] += a0 * p.w;
            acc0[1][0] += a1 * p.x; acc0[1][1] += a1 * p.y; acc0[1][2] += a1 * p.z; acc0[1][3] += a1 * p.w;
            acc0[2][0] += a2 * p.x; acc0[2][1] += a2 * p.y; acc0[2][2] += a2 * p.z; acc0[2][3] += a2 * p.w;
            acc0[3][0] += a3 * p.x; acc0[3][1] += a3 * p.y; acc0[3][2] += a3 * p.z; acc0[3][3] += a3 * p.w;
            acc1[0][0] += a0 * q.x; acc1[0][1] += a0 * q.y; acc1[0][2] += a0 * q.z; acc1[0][3] += a0 * q.w;
            acc1[1][0] += a1 * q.x; acc1[1][1] += a1 * q.y; acc1[1][2] += a1 * q.z; acc1[1][3] += a1 * q.w;
            acc1[2][0] += a2 * q.x; acc1[2][1] += a2 * q.y; acc1[2][2] += a2 * q.z; acc1[2][3] += a2 * q.w;
            acc1[3][0] += a3 * q.x; acc1[3][1] += a3 * q.y; acc1[3][2] += a3 * q.z; acc1[3][3] += a3 * q.w;
        }
        __syncthreads();
    }

    #pragma unroll
    for (int i = 0; i < 4; ++i) {
        const int row = bm + ty * 4 + i;
        if (row >= M) continue;
        #pragma unroll
        for (int j = 0; j < 4; ++j) {
            const int col = bn + tx * 4 + j;
            if (col < dout) {
                C0[(size_t)row * dout + col] = acc0[i][j] + b0[col];
                C1[(size_t)row * dout + col] = acc1[i][j] + b1[col];
            }
        }
    }
}

// ---------------- gathers over fp16 h1 + fp16 h0, fp16 output ----------------
__global__ __launch_bounds__(256) void gather_d192_h(
    const _Float16* __restrict__ h0, const __half2* __restrict__ h1,
    const int* __restrict__ rowptr, const int* __restrict__ adj,
    const float* __restrict__ dinv, _Float16* __restrict__ out)
{
    const int v = blockIdx.x * 4 + (threadIdx.x >> 6);
    if (v >= NV) return;
    const int lane = threadIdx.x & 63;
    const int sub = lane >> 5;
    const int cu = (lane & 31) * 3;        // half2 column
    const int s = rowptr[v], e = rowptr[v + 1];

    float2 a0 = {0.f, 0.f}, a1 = {0.f, 0.f}, a2 = {0.f, 0.f};

    int j = s;
    const int jend = s + ((e - s) & ~7);
    for (; j < jend; j += 8) {
        const int u0 = adj[j + 0 + sub];
        const int u1 = adj[j + 2 + sub];
        const int u2 = adj[j + 4 + sub];
        const int u3 = adj[j + 6 + sub];
        const __half2* r0 = h1 + (size_t)u0 * 96 + cu;
        const __half2* r1 = h1 + (size_t)u1 * 96 + cu;
        const __half2* r2 = h1 + (size_t)u2 * 96 + cu;
        const __half2* r3 = h1 + (size_t)u3 * 96 + cu;
        const __half2 x00 = r0[0], x01 = r0[1], x02 = r0[2];
        const __half2 x10 = r1[0], x11 = r1[1], x12 = r1[2];
        const __half2 x20 = r2[0], x21 = r2[1], x22 = r2[2];
        const __half2 x30 = r3[0], x31 = r3[1], x32 = r3[2];
        float2 p;
        p = __half22float2(x00); a0.x += p.x; a0.y += p.y;
        p = __half22float2(x01); a1.x += p.x; a1.y += p.y;
        p = __half22float2(x02); a2.x += p.x; a2.y += p.y;
        p = __half22float2(x10); a0.x += p.x; a0.y += p.y;
        p = __half22float2(x11); a1.x += p.x; a1.y += p.y;
        p = __half22float2(x12); a2.x += p.x; a2.y += p.y;
        p = __half22float2(x20); a0.x += p.x; a0.y += p.y;
        p = __half22float2(x21); a1.x += p.x; a1.y += p.y;
        p = __half22float2(x22); a2.x += p.x; a2.y += p.y;
        p = __half22float2(x30); a0.x += p.x; a0.y += p.y;
        p = __half22float2(x31); a1.x += p.x; a1.y += p.y;
        p = __half22float2(x32); a2.x += p.x; a2.y += p.y;
    }
    for (; j < e; j += 2) {
        const int jj = j + sub;
        if (jj < e) {
            const __half2* r = h1 + (size_t)adj[jj] * 96 + cu;
            float2 p;
            p = __half22float2(r[0]); a0.x += p.x; a0.y += p.y;
            p = __half22float2(r[1]); a1.x += p.x; a1.y += p.y;
            p = __half22float2(r[2]); a2.x += p.x; a2.y += p.y;
        }
    }

    a0.x += __shfl_xor(a0.x, 32); a0.y += __shfl_xor(a0.y, 32);
    a1.x += __shfl_xor(a1.x, 32); a1.y += __shfl_xor(a1.y, 32);
    a2.x += __shfl_xor(a2.x, 32); a2.y += __shfl_xor(a2.y, 32);

    if (sub == 0) {
        const float di = dinv[v];
        const size_t base = (size_t)v * 192 + (size_t)cu * 2;
        const f16x2 z0 = *reinterpret_cast<const f16x2*>(h0 + base + 0);
        const f16x2 z1 = *reinterpret_cast<const f16x2*>(h0 + base + 2);
        const f16x2 z2 = *reinterpret_cast<const f16x2*>(h0 + base + 4);
        f16x2 o0, o1, o2;
        o0[0] = (_Float16)fmaxf(((float)z0[0] + a0.x) * di, 0.f);
        o0[1] = (_Float16)fmaxf(((float)z0[1] + a0.y) * di, 0.f);
        o1[0] = (_Float16)fmaxf(((float)z1[0] + a1.x) * di, 0.f);
        o1[1] = (_Float16)fmaxf(((float)z1[1] + a1.y) * di, 0.f);
        o2[0] = (_Float16)fmaxf(((float)z2[0] + a2.x) * di, 0.f);
        o2[1] = (_Float16)fmaxf(((float)z2[1] + a2.y) * di, 0.f);
        *reinterpret_cast<f16x2*>(out + base + 0) = o0;
        *reinterpret_cast<f16x2*>(out + base + 2) = o1;
        *reinterpret_cast<f16x2*>(out + base + 4) = o2;
    }
}

__global__ __launch_bounds__(256) void gather_d128_h(
    const _Float16* __restrict__ h0, const __half2* __restrict__ h1,
    const int* __restrict__ rowptr, const int* __restrict__ adj,
    const float* __restrict__ dinv, _Float16* __restrict__ out)
{
    const int v = blockIdx.x * 4 + (threadIdx.x >> 6);
    if (v >= NV) return;
    const int lane = threadIdx.x & 63;
    const int sub = lane >> 4;             // 0..3
    const int cu = (lane & 15) * 4;        // half2 column
    const int s = rowptr[v], e = rowptr[v + 1];

    float acc[8] = {};

    int j = s;
    const int jend = s + ((e - s) & ~15);
    for (; j < jend; j += 16) {
        const int u0 = adj[j + 0 + sub];
        const int u1 = adj[j + 4 + sub];
        const int u2 = adj[j + 8 + sub];
        const int u3 = adj[j + 12 + sub];
        const int4 w0 = *reinterpret_cast<const int4*>(h1 + (size_t)u0 * 64 + cu);
        const int4 w1 = *reinterpret_cast<const int4*>(h1 + (size_t)u1 * 64 + cu);
        const int4 w2 = *reinterpret_cast<const int4*>(h1 + (size_t)u2 * 64 + cu);
        const int4 w3 = *reinterpret_cast<const int4*>(h1 + (size_t)u3 * 64 + cu);
        #pragma unroll
        for (int t = 0; t < 4; ++t) {
            const float2 p0 = __half22float2(*(const __half2*)(&(&w0.x)[t]));
            const float2 p1 = __half22float2(*(const __half2*)(&(&w1.x)[t]));
            const float2 p2 = __half22float2(*(const __half2*)(&(&w2.x)[t]));
            const float2 p3 = __half22float2(*(const __half2*)(&(&w3.x)[t]));
            acc[2 * t + 0] += (p0.x + p1.x) + (p2.x + p3.x);
            acc[2 * t + 1] += (p0.y + p1.y) + (p2.y + p3.y);
        }
    }
    for (; j < e; j += 4) {
        const int jj = j + sub;
        if (jj < e) {
            const int4 w0 = *reinterpret_cast<const int4*>(h1 + (size_t)adj[jj] * 64 + cu);
            #pragma unroll
            for (int t = 0; t < 4; ++t) {
                const float2 p = __half22float2(*(const __half2*)(&(&w0.x)[t]));
                acc[2 * t + 0] += p.x;
                acc[2 * t + 1] += p.y;
            }
        }
    }

    #pragma unroll
    for (int t = 0; t < 8; ++t) {
        acc[t] += __shfl_xor(acc[t], 16);
        acc[t] += __shfl_xor(acc[t], 32);
    }

    if (sub == 0) {
        const float di = dinv[v];
        const size_t base = (size_t)v * 128 + (size_t)cu * 2;
        const f16x8 z = *reinterpret_cast<const f16x8*>(h0 + base);
        f16x8 o;
        #pragma unroll
        for (int t = 0; t < 8; ++t)
            o[t] = (_Float16)fmaxf(((float)z[t] + acc[t]) * di, 0.f);
        *reinterpret_cast<f16x8*>(out + base) = o;
    }
}

__global__ __launch_bounds__(256) void gather_d64_h(
    const _Float16* __restrict__ h0, const __half2* __restrict__ h1,
    const int* __restrict__ rowptr, const int* __restrict__ adj,
    const float* __restrict__ dinv, _Float16* __restrict__ out)
{
    const int v = blockIdx.x * 4 + (threadIdx.x >> 6);
    if (v >= NV) return;
    const int lane = threadIdx.x & 63;
    const int sub = lane >> 4;             // 0..3
    const int cu = (lane & 15) * 2;        // half2 column
    const int s = rowptr[v], e = rowptr[v + 1];

    float acc[4] = {};

    int j = s;
    const int jend = s + ((e - s) & ~15);
    for (; j < jend; j += 16) {
        const int u0 = adj[j + 0 + sub];
        const int u1 = adj[j + 4 + sub];
        const int u2 = adj[j + 8 + sub];
        const int u3 = adj[j + 12 + sub];
        const int2 w0 = *reinterpret_cast<const int2*>(h1 + (size_t)u0 * 32 + cu);
        const int2 w1 = *reinterpret_cast<const int2*>(h1 + (size_t)u1 * 32 + cu);
        const int2 w2 = *reinterpret_cast<const int2*>(h1 + (size_t)u2 * 32 + cu);
        const int2 w3 = *reinterpret_cast<const int2*>(h1 + (size_t)u3 * 32 + cu);
        #pragma unroll
        for (int t = 0; t < 2; ++t) {
            const float2 p0 = __half22float2(*(const __half2*)(&(&w0.x)[t]));
            const float2 p1 = __half22float2(*(const __half2*)(&(&w1.x)[t]));
            const float2 p2 = __half22float2(*(const __half2*)(&(&w2.x)[t]));
            const float2 p3 = __half22float2(*(const __half2*)(&(&w3.x)[t]));
            acc[2 * t + 0] += (p0.x + p1.x) + (p2.x + p3.x);
            acc[2 * t + 1] += (p0.y + p1.y) + (p2.y + p3.y);
        }
    }
    for (; j < e; j += 4) {
        const int jj = j + sub;
        if (jj < e) {
            const int2 w0 = *reinterpret_cast<const int2*>(h1 + (size_t)adj[jj] * 32 + cu);
            #pragma unroll
            for (int t = 0; t < 2; ++t) {
                const float2 p = __half22float2(*(const __half2*)(&(&w0.x)[t]));
                acc[2 * t + 0] += p.x;
                acc[2 * t + 1] += p.y;
            }
        }
    }

    #pragma unroll
    for (int t = 0; t < 4; ++t) {
        acc[t] += __shfl_xor(acc[t], 16);
        acc[t] += __shfl_xor(acc[t], 32);
    }

    if (sub == 0) {
        const float di = dinv[v];
        const size_t base = (size_t)v * 64 + (size_t)cu * 2;
        const f16x4 z = *reinterpret_cast<const f16x4*>(h0 + base);
        f16x4 o;
        #pragma unroll
        for (int t = 0; t < 4; ++t)
            o[t] = (_Float16)fmaxf(((float)z[t] + acc[t]) * di, 0.f);
        *reinterpret_cast<f16x4*>(out + base) = o;
    }
}

__global__ __launch_bounds__(256) void gather_d3(
    const float* __restrict__ h0, const float* __restrict__ h1,
    const int* __restrict__ rowptr, const int* __restrict__ adj,
    const float* __restrict__ dinv, float* __restrict__ out)
{
    const int v = blockIdx.x * 4 + (threadIdx.x >> 6);
    if (v >= NV) return;
    const int lane = threadIdx.x & 63;
    const int s = rowptr[v], e = rowptr[v + 1];
    float a0 = 0.f, a1 = 0.f, a2 = 0.f;
    for (int j = s + lane; j < e; j += 64) {
        const float3 r = *reinterpret_cast<const float3*>(h1 + (size_t)adj[j] * 3);
        a0 += r.x; a1 += r.y; a2 += r.z;
    }
    #pragma unroll
    for (int off = 1; off < 64; off <<= 1) {
        a0 += __shfl_xor(a0, off);
        a1 += __shfl_xor(a1, off);
        a2 += __shfl_xor(a2, off);
    }
    if (lane == 0) {
        const float di = dinv[v];
        const size_t base = (size_t)v * 3;
        out[base + 0] = (h0[base + 0] + a0) * di;
        out[base + 1] = (h0[base + 1] + a1) * di;
        out[base + 2] = (h0[base + 2] + a2) * di;
    }
}

extern "C" void kernel_launch(void* const* d_in, const int* in_sizes, int n_in,
                              void* d_out, int out_size, void* d_ws, size_t ws_size,
                              hipStream_t stream) {
    const float* features = (const float*)d_in[0];
    const int*   edges    = (const int*)d_in[1];

    char* ws = (char*)d_ws;
    size_t off = 0;
    auto alloc = [&](size_t bytes) {
        void* p = ws + off;
        off = (off + bytes + 255) & ~(size_t)255;
        return p;
    };
    int*      deg    = (int*)alloc((size_t)NV * sizeof(int));
    float*    dinv   = (float*)alloc((size_t)NV * sizeof(float));
    int*      rowptr = (int*)alloc((size_t)(NV + 1) * sizeof(int));
    int*      fill   = (int*)alloc((size_t)NV * sizeof(int));
    int*      bsum   = (int*)alloc(256 * sizeof(int));
    int*      adj    = (int*)alloc((size_t)2 * NE * sizeof(int));
    _Float16* hC0    = (_Float16*)alloc((size_t)NV * 192 * sizeof(_Float16)); // h0 (fp16)
    _Float16* hC1    = (_Float16*)alloc((size_t)NV * 192 * sizeof(_Float16)); // h1 (fp16)
    _Float16* bufX1  = (_Float16*)alloc((size_t)NV * 192 * sizeof(_Float16)); // x after L0 / L2
    _Float16* bufX2  = (_Float16*)alloc((size_t)NV * 128 * sizeof(_Float16)); // x after L1
    float*    c0f    = (float*)alloc((size_t)NV * 3 * sizeof(float));         // L3 h0
    float*    c1f    = (float*)alloc((size_t)NV * 3 * sizeof(float));         // L3 h1
    // pre-transposed fp16 weights [dout][din]
    _Float16* wt0_0  = (_Float16*)alloc((size_t)192 * 256 * sizeof(_Float16));
    _Float16* wt1_0  = (_Float16*)alloc((size_t)192 * 256 * sizeof(_Float16));
    _Float16* wt0_1  = (_Float16*)alloc((size_t)128 * 192 * sizeof(_Float16));
    _Float16* wt1_1  = (_Float16*)alloc((size_t)128 * 192 * sizeof(_Float16));
    _Float16* wt0_2  = (_Float16*)alloc((size_t)64 * 128 * sizeof(_Float16));
    _Float16* wt1_2  = (_Float16*)alloc((size_t)64 * 128 * sizeof(_Float16));

    // ---- CSR build ----
    hipMemsetAsync(deg, 0, (size_t)NV * sizeof(int), stream);
    degree_count<<<(2 * NE + 255) / 256, 256, 0, stream>>>(edges, deg, 2 * NE);
    scan_block<<<NBLK, SCAN_B, 0, stream>>>(deg, rowptr, bsum, NV);
    scan_top<<<1, 128, 0, stream>>>(bsum, NBLK);
    finalize_rowptr<<<NBLK, SCAN_B, 0, stream>>>(rowptr, bsum, deg, fill, dinv, NV);
    fill_adj<<<(NE + 255) / 256, 256, 0, stream>>>(edges, fill, adj, NE);

    // ---- weight convert/transpose (tiny) ----
    convert_wt<<<(256 * 192 + 255) / 256, 256, 0, stream>>>((const float*)d_in[2],  wt0_0, 256, 192);
    convert_wt<<<(256 * 192 + 255) / 256, 256, 0, stream>>>((const float*)d_in[4],  wt1_0, 256, 192);
    convert_wt<<<(192 * 128 + 255) / 256, 256, 0, stream>>>((const float*)d_in[6],  wt0_1, 192, 128);
    convert_wt<<<(192 * 128 + 255) / 256, 256, 0, stream>>>((const float*)d_in[8],  wt1_1, 192, 128);
    convert_wt<<<(128 * 64 + 255) / 256, 256, 0, stream>>>((const float*)d_in[10], wt0_2, 128, 64);
    convert_wt<<<(128 * 64 + 255) / 256, 256, 0, stream>>>((const float*)d_in[12], wt1_2, 128, 64);

    const int gatherGrid = (NV + 3) / 4;
    const int gemmGrid = (NV + 63) / 64;

    // ---- layer 0: 256 -> 192 ----
    gemm_dual_reg<float, 256, 3><<<gemmGrid, 256, 0, stream>>>(
        features, wt0_0, (const float*)d_in[3], wt1_0, (const float*)d_in[5],
        hC0, hC1, NV);
    gather_d192_h<<<gatherGrid, 256, 0, stream>>>(hC0, (const __half2*)hC1,
                                                  rowptr, adj, dinv, bufX1);

    // ---- layer 1: 192 -> 128 ----
    gemm_dual_reg<_Float16, 192, 2><<<gemmGrid, 256, 0, stream>>>(
        bufX1, wt0_1, (const float*)d_in[7], wt1_1, (const float*)d_in[9],
        hC0, hC1, NV);
    gather_d128_h<<<gatherGrid, 256, 0, stream>>>(hC0, (const __half2*)hC1,
                                                  rowptr, adj, dinv, bufX2);

    // ---- layer 2: 128 -> 64 ----
    gemm_dual_reg<_Float16, 128, 1><<<gemmGrid, 256, 0, stream>>>(
        bufX2, wt0_2, (const float*)d_in[11], wt1_2, (const float*)d_in[13],
        hC0, hC1, NV);
    gather_d64_h<<<gatherGrid, 256, 0, stream>>>(hC0, (const __half2*)hC1,
                                                 rowptr, adj, dinv, bufX1);

    // ---- layer 3: 64 -> 3 (fp32 epilogue path) ----
    {
        dim3 grid((NV + BM - 1) / BM, 1);
        gemm_dual_bias_f32<<<grid, 256, 0, stream>>>(
            bufX1,
            (const float*)d_in[14], (const float*)d_in[15],
            (const float*)d_in[16], (const float*)d_in[17],
            c0f, c1f, NV, 64, 3);
        gather_d3<<<gatherGrid, 256, 0, stream>>>(c0f, c1f, rowptr, adj, dinv, (float*)d_out);
    }
}